// Round 5
// baseline (425.583 us; speedup 1.0000x reference)
//
#include <hip/hip_runtime.h>
#include <hip/hip_fp16.h>
#include <math.h>

#define N_NODES 50000
#define N_EDGES 800000
#define NEG_SLOPE 0.2f

#define BKT_SHIFT 7
#define N_BKT 512                      // pow2 upper bound; used: ceil(50000/128)=391
#define NB_CSR ((N_NODES + 127) / 128) // 391
#define CHUNK 2048                     // edges per phase-A block
#define BCAP 4096                      // fixed bucket capacity (mean 2048, 45 sigma)
#define PB_CAP 4096
#define G1_BLOCKS (((N_NODES + 127) / 128) * 2)   // 782 gemm-1 blocks (2 n-tiles)

typedef _Float16 v8h __attribute__((ext_vector_type(8)));
typedef _Float16 h4  __attribute__((ext_vector_type(4)));
typedef _Float16 h2  __attribute__((ext_vector_type(2)));
typedef float f32x4 __attribute__((ext_vector_type(4)));
typedef float f32x2 __attribute__((ext_vector_type(2)));

static inline int cdiv(long long a, int b) { return (int)((a + b - 1) / b); }

// DPP-fused butterfly add step (VALU add reading neighbor via DPP, no LDS).
// CTRL: 0xB1 = quad_perm[1,0,3,2] (xor1), 0x4E = quad_perm[2,3,0,1] (xor2),
// 0x141 = row_half_mirror (lane i <-> 7-i within each 8-lane half).
template<int CTRL>
static __device__ __forceinline__ float dpp_xadd(float s) {
    int t = __builtin_amdgcn_mov_dpp(__builtin_bit_cast(int, s), CTRL, 0xf, 0xf, true);
    return s + __builtin_bit_cast(float, t);
}

// ========= weight packing W[K][N] f32 -> Wt[N][K] f16, plus bcnt zero-init =========
__global__ void pack_weights_zero(const float* __restrict__ W1l, const float* __restrict__ W1r,
                                  const float* __restrict__ W2l, const float* __restrict__ W2r,
                                  const float* __restrict__ W3l, const float* __restrict__ W3r,
                                  _Float16* __restrict__ Wt1, _Float16* __restrict__ Wt2,
                                  _Float16* __restrict__ Wt3, int* __restrict__ bcnt) {
    int id = blockIdx.x * blockDim.x + threadIdx.x;
    if (id < 32768) {                       // Wt1: [256][128]
        int n = id >> 7, k = id & 127;
        Wt1[id] = (_Float16)(n < 128 ? W1l[k * 128 + n] : W1r[k * 128 + n - 128]);
    } else if (id < 65536) {                // Wt2: [256][128]
        int j = id - 32768; int n = j >> 7, k = j & 127;
        Wt2[j] = (_Float16)(n < 128 ? W2l[k * 128 + n] : W2r[k * 128 + n - 128]);
    } else if (id < 81920) {                // Wt3: [128][128]
        int j = id - 65536; int n = j >> 7, k = j & 127;
        Wt3[j] = (_Float16)(n < 64 ? W3l[k * 64 + n] : W3r[k * 64 + n - 64]);
    } else if (id < 81920 + N_BKT) {
        bcnt[id - 81920] = 0;
    }
}

// ===== Phase A: LDS bucket sort per 2048-edge chunk, coalesced run append =====
__global__ __launch_bounds__(512) void bucket_scatter(const int* __restrict__ esrc,
                                                      const int* __restrict__ edst,
                                                      int* __restrict__ bcnt,
                                                      int2* __restrict__ tmp) {
    __shared__ int lhist[N_BKT];
    __shared__ int lscan[N_BKT];
    __shared__ int lofs[N_BKT];
    __shared__ int lcur[N_BKT];
    __shared__ int gbase[N_BKT];
    __shared__ int2 lpair[CHUNK];
    int tid = threadIdx.x;
    int base_e = blockIdx.x * CHUNK;
    int count = min(CHUNK, N_EDGES - base_e);

    if (tid < N_BKT) lhist[tid] = 0;
    __syncthreads();

    int e0 = base_e + tid * 4;
    int4 s4 = {0, 0, 0, 0}, d4 = {0, 0, 0, 0};
    int nmine = 0;
    if (e0 + 3 < N_EDGES && e0 + 3 < base_e + count) {
        s4 = *(const int4*)(esrc + e0);
        d4 = *(const int4*)(edst + e0);
        nmine = 4;
    } else if (e0 < N_EDGES) {
        nmine = min(N_EDGES - e0, 4);
        const int* sp = esrc + e0;
        const int* dp = edst + e0;
        if (nmine > 0) { s4.x = sp[0]; d4.x = dp[0]; }
        if (nmine > 1) { s4.y = sp[1]; d4.y = dp[1]; }
        if (nmine > 2) { s4.z = sp[2]; d4.z = dp[2]; }
    }
    int ds[4] = {d4.x, d4.y, d4.z, d4.w};
    int ss[4] = {s4.x, s4.y, s4.z, s4.w};
#pragma unroll
    for (int u = 0; u < 4; ++u)
        if (u < nmine) atomicAdd(&lhist[ds[u] >> BKT_SHIFT], 1);
    __syncthreads();

    // exclusive scan over N_BKT in LDS (Hillis-Steele, 512 threads = N_BKT)
    int v = lhist[tid];
    lscan[tid] = v;
    __syncthreads();
    for (int st = 1; st < N_BKT; st <<= 1) {
        int t = (tid >= st) ? lscan[tid - st] : 0;
        __syncthreads();
        lscan[tid] += t;
        __syncthreads();
    }
    {
        int excl = lscan[tid] - v;
        lofs[tid] = excl;
        lcur[tid] = excl;
        if (v > 0) gbase[tid] = tid * BCAP + atomicAdd(&bcnt[tid], v);
    }
    __syncthreads();

#pragma unroll
    for (int u = 0; u < 4; ++u)
        if (u < nmine) {
            int b = ds[u] >> BKT_SHIFT;
            int p = atomicAdd(&lcur[b], 1);
            lpair[p] = make_int2(ss[u], ds[u]);
        }
    __syncthreads();

    for (int j = tid; j < count; j += 512) {
        int2 pr = lpair[j];
        int b = pr.y >> BKT_SHIFT;
        int idx = gbase[b] + (j - lofs[b]);
        if (idx < (b + 1) * BCAP) tmp[idx] = pr;   // 45-sigma overflow guard
    }
}

// ===== Merged dispatch: blocks [0,391) finalize CSR; blocks [391, 391+782) run layer-1 GEMM =====
// R15: n-tile (by) fastest-varying so both n-tiles of a bx run temporally adjacent -> the
// f32 A rows (25.6MB) are read once from HBM, second read hits L2/L3.
__global__ __launch_bounds__(256, 2) void csr_and_gemm1(const int* __restrict__ bcnt,
                                                        const int2* __restrict__ tmp,
                                                        int* __restrict__ off,
                                                        int* __restrict__ csr,
                                                        const float* __restrict__ A,
                                                        const _Float16* __restrict__ Bt,
                                                        _Float16* __restrict__ C) {
    __shared__ int red[256];
    __shared__ int lcnt[128];
    __shared__ int sc[128];
    __shared__ int loff[129];
    __shared__ int lcur[128];
    __shared__ int lcsr[PB_CAP];
    int tid = threadIdx.x;

    if (blockIdx.x >= NB_CSR) {
        // ---------------- layer-1 GEMM part (A = f32 input, cast in-register) ------------
        int gb = blockIdx.x - NB_CSR;
        int bx = gb >> 1;               // R15: by fastest for A-row temporal reuse
        int by = gb & 1;                // 0 or 1
        int w = tid >> 6, lane = tid & 63;
        int m0 = bx * 128 + (w & 1) * 64;
        int n0 = by * 128 + (w >> 1) * 64;
        int q = lane >> 4, li = lane & 15;
        f32x4 acc[4][4] = {};
        const float* Ap[4];
#pragma unroll
        for (int a = 0; a < 4; ++a) {
            int row = m0 + 16 * a + li;
            if (row > N_NODES - 1) row = N_NODES - 1;
            Ap[a] = A + (size_t)row * 128 + q * 8;
        }
        const _Float16* Bp = Bt + (size_t)(n0 + li) * 128 + q * 8;
#pragma unroll
        for (int kt = 0; kt < 4; ++kt) {
            v8h af[4], bf[4];
#pragma unroll
            for (int a = 0; a < 4; ++a) {
                float4 lo = *(const float4*)(Ap[a] + kt * 32);
                float4 hi = *(const float4*)(Ap[a] + kt * 32 + 4);
                v8h t;
                t[0] = (_Float16)lo.x; t[1] = (_Float16)lo.y; t[2] = (_Float16)lo.z; t[3] = (_Float16)lo.w;
                t[4] = (_Float16)hi.x; t[5] = (_Float16)hi.y; t[6] = (_Float16)hi.z; t[7] = (_Float16)hi.w;
                af[a] = t;
            }
#pragma unroll
            for (int b = 0; b < 4; ++b) bf[b] = *(const v8h*)(Bp + (size_t)(16 * b) * 128 + kt * 32);
#pragma unroll
            for (int a = 0; a < 4; ++a)
#pragma unroll
                for (int b = 0; b < 4; ++b)
                    acc[a][b] = __builtin_amdgcn_mfma_f32_16x16x32_f16(bf[b], af[a], acc[a][b], 0, 0, 0);
        }
#pragma unroll
        for (int a = 0; a < 4; ++a) {
            int m = m0 + 16 * a + li;
            if (m < N_NODES) {
#pragma unroll
                for (int b = 0; b < 4; ++b) {
                    h4 t;
                    t[0] = (_Float16)acc[a][b][0]; t[1] = (_Float16)acc[a][b][1];
                    t[2] = (_Float16)acc[a][b][2]; t[3] = (_Float16)acc[a][b][3];
                    *(h4*)(C + (size_t)m * 256 + n0 + 16 * b + 4 * q) = t;
                }
            }
        }
        return;
    }

    // ---------------- CSR finalize part ----------------
    int b = blockIdx.x;
    int d0 = b << BKT_SHIFT;
    int dend = min(d0 + 128, N_NODES);
    int nn = dend - d0;

    int pre = 0;
    for (int i = tid; i < b; i += 256) pre += bcnt[i];
    red[tid] = pre;
    __syncthreads();
    for (int st = 128; st > 0; st >>= 1) {
        if (tid < st) red[tid] += red[tid + st];
        __syncthreads();
    }
    int base = red[0];
    __syncthreads();

    int n = min(bcnt[b], BCAP);
    int tbase = b * BCAP;

    if (tid < 128) lcnt[tid] = 0;
    __syncthreads();
    for (int j = tid; j < n; j += 256) {
        int dl = tmp[tbase + j].y - d0;
        atomicAdd(&lcnt[dl], 1);
    }
    __syncthreads();

    if (tid < 128) sc[tid] = lcnt[tid];
    __syncthreads();
    for (int st = 1; st < 128; st <<= 1) {
        int t = (tid < 128 && tid >= st) ? sc[tid - st] : 0;
        __syncthreads();
        if (tid < 128) sc[tid] += t;
        __syncthreads();
    }
    if (tid < 128) loff[tid + 1] = sc[tid];
    if (tid == 0) loff[0] = 0;
    if (tid < 128) lcur[tid] = 0;
    __syncthreads();

    if (tid < nn) off[d0 + tid] = base + loff[tid];
    if (tid == 0 && dend == N_NODES) off[N_NODES] = base + loff[nn];

    for (int j = tid; j < n; j += 256) {
        int2 pr = tmp[tbase + j];
        int dl = pr.y - d0;
        int r = atomicAdd(&lcur[dl], 1);
        int pos = loff[dl] + r;
        if (pos < PB_CAP) lcsr[pos] = pr.x;
    }
    __syncthreads();
    for (int j = tid; j < n; j += 256) csr[base + j] = lcsr[j];
}

// ===== MFMA GEMM (layers 2,3): C[M][NT](f16) = A[M][128] @ Bt[NT][128]^T =====
// R15: 1-D grid, n-tile fastest -> both n-tiles of a bx temporally adjacent (A reuse in L2/L3).
// R19: REVERT launch_bounds to 3 (R17's 4 caps VGPR at 128 < ~140 needed -> spill suspect
// for R18's unexplained +6us; 3 waves = 168-VGPR cap, proven config).
template<int NT>
__global__ __launch_bounds__(256, 3) void gemm_xlr(const _Float16* __restrict__ A,
                                                   const _Float16* __restrict__ Bt,
                                                   _Float16* __restrict__ C) {
    constexpr int NY = NT / 128;
    int bx = blockIdx.x / NY;
    int by = blockIdx.x % NY;
    int w = threadIdx.x >> 6, lane = threadIdx.x & 63;
    int m0 = bx * 128 + (w & 1) * 64;
    int n0 = by * 128 + (w >> 1) * 64;
    int q = lane >> 4, li = lane & 15;
    f32x4 acc[4][4] = {};
    const _Float16* Ap[4];
#pragma unroll
    for (int a = 0; a < 4; ++a) {
        int row = m0 + 16 * a + li;
        if (row > N_NODES - 1) row = N_NODES - 1;  // clamp: no OOB reads
        Ap[a] = A + (size_t)row * 128 + q * 8;
    }
    const _Float16* Bp = Bt + (size_t)(n0 + li) * 128 + q * 8;
#pragma unroll
    for (int kt = 0; kt < 4; ++kt) {
        v8h af[4], bf[4];
#pragma unroll
        for (int a = 0; a < 4; ++a) af[a] = *(const v8h*)(Ap[a] + kt * 32);
#pragma unroll
        for (int b = 0; b < 4; ++b) bf[b] = *(const v8h*)(Bp + (size_t)(16 * b) * 128 + kt * 32);
#pragma unroll
        for (int a = 0; a < 4; ++a)
#pragma unroll
            for (int b = 0; b < 4; ++b)
                acc[a][b] = __builtin_amdgcn_mfma_f32_16x16x32_f16(bf[b], af[a], acc[a][b], 0, 0, 0);
    }
#pragma unroll
    for (int a = 0; a < 4; ++a) {
        int m = m0 + 16 * a + li;
        if (m < N_NODES) {
#pragma unroll
            for (int b = 0; b < 4; ++b) {
                h4 t;
                t[0] = (_Float16)acc[a][b][0]; t[1] = (_Float16)acc[a][b][1];
                t[2] = (_Float16)acc[a][b][2]; t[3] = (_Float16)acc[a][b][3];
                *(h4*)(C + (size_t)m * NT + n0 + 16 * b + 4 * q) = t;
            }
        }
    }
}

// ========== fused GATv2: persistent waves, 2-ahead cross-NODE software pipeline ==========
// R15-R18 lesson: inner-loop VALU dieting is flat (R16/R18), adding VALU hurts (R17) ->
// the kernel sits at a latency/issue balance. The REAL serial cost is the per-node
// pointer chain: off[node] -> csr[...] -> row gather (~1000-1300 cyc) before ~270 cyc of
// compute, one node per wave. R19: persistent waves (each handles ~8 nodes) with the
// chain pipelined ACROSS nodes:
//   A: issue off/xr loads for node k+2          (independent)
//   C: issue csr-idx prologue for node k+1      (its off issued a full node ago -> ready)
//   D: edge loop for node k                     (R18 3-slot modulo schedule)
//   E: issue row loads for node k+1             (indices returned during D)
//   F: epilogue for node k                      (hides part of E's latency)
// Exposed per-node chain drops ~1300 -> ~300 cyc. State ~70 VGPR -> launch_bounds(128,6)
// (measured occupancy was ~20 waves/CU anyway; 24-wave cap costs nothing, avoids spill).
template<int HOUT, typename OUT_T>
__global__ __launch_bounds__(128, 6) void fused_gat(
    const _Float16* __restrict__ XLR,   // [N][2*HOUT] = [xl | xr]
    const int* __restrict__ off, const int* __restrict__ csr,
    const float* __restrict__ att, const float* __restrict__ bias,
    OUT_T* __restrict__ out) {          // [N][HOUT]
    constexpr int VEC = 8;
    constexpr int LPE = HOUT / VEC;     // lanes per edge (16 or 8)
    constexpr int EPW = 64 / LPE;       // edge groups per wave (4 or 8)
    constexpr int ST = 2 * HOUT;
    int wave = threadIdx.x >> 6, lane = threadIdx.x & 63;
    int wid = blockIdx.x * (blockDim.x >> 6) + wave;
    int NW = gridDim.x * (blockDim.x >> 6);
    int g = lane / LPE;
    int lg = lane % LPE;
    int cb = lg * VEC;

    constexpr float LOG2E = 1.44269504088896340736f;
    f32x2 at2[4];
#pragma unroll
    for (int j = 0; j < 4; ++j) {
        at2[j][0] = att[cb + 2 * j] * LOG2E;       // fold log2e -> exp2 domain
        at2[j][1] = att[cb + 2 * j + 1] * LOG2E;
    }

    const _Float16* Xcb = XLR + cb;

    // clamped csr index for position pos (pos >= 1): clamp(pos-1, 0, pm)
    auto cidx = [](int pos, int pm) -> int {
        int i = pos - 1;
        i = i > pm ? pm : i;
        return i < 0 ? 0 : i;
    };
    // clamped row load (src index garbage-safe)
    auto rowload = [&](int s) -> v8h {
        s = s < 0 ? 0 : s;
        s = s > N_NODES - 1 ? N_NODES - 1 : s;
        return *(const v8h*)(Xcb + (size_t)s * ST);
    };

    int node = wid;
    if (node >= N_NODES) return;

    // ---- cold prologue for first node ----
    int eoff = off[node], eend = off[node + 1];
    v8h xrh = *(const v8h*)(XLR + (size_t)node * ST + HOUT + cb);
    int P = eend - eoff + 1;            // position 0 = self-loop, 1..deg = csr edges
    const int* cp = csr + eoff;
    int pmax = P - 2;
    int si3 = cp[cidx(g + 3 * EPW, pmax)];
    int s0c = (g == 0) ? node : cp[cidx(g, pmax)];
    v8h ah0 = rowload(s0c);
    v8h ah1 = rowload(cp[cidx(g + EPW, pmax)]);
    v8h ah2 = rowload(cp[cidx(g + 2 * EPW, pmax)]);

    // next-node off/xr prefetch (1-ahead)
    int nnode = node + NW;
    int n_eoff = 0, n_eend = 0;
    v8h n_xrh = {};
    if (nnode < N_NODES) {
        n_eoff = off[nnode]; n_eend = off[nnode + 1];
        n_xrh = *(const v8h*)(XLR + (size_t)nnode * ST + HOUT + cb);
    }

    while (true) {
        // ---- A: issue 2-ahead off/xr for node k+2 ----
        int n2 = node + 2 * NW;
        int a_eoff = 0, a_eend = 0;
        v8h a_xrh = {};
        if (n2 < N_NODES) {
            a_eoff = off[n2]; a_eend = off[n2 + 1];
            a_xrh = *(const v8h*)(XLR + (size_t)n2 * ST + HOUT + cb);
        }

        // ---- B: convert current xr (xrh issued >= 1 node ago -> ready) ----
        f32x2 xr2[4];
        {
            const h2* x2 = (const h2*)&xrh;
#pragma unroll
            for (int j = 0; j < 4; ++j) { xr2[j][0] = (float)x2[j][0]; xr2[j][1] = (float)x2[j][1]; }
        }

        // ---- C: issue csr-idx prologue for node k+1 (n_eoff ready) ----
        bool has_next = nnode < N_NODES;
        int n_pmax = 0, n_si3 = 0, n_s0 = 0, n_i1 = 0, n_i2 = 0;
        const int* ncp = nullptr;
        if (has_next) {
            int nP = n_eend - n_eoff + 1;
            ncp = csr + n_eoff;
            n_pmax = nP - 2;
            n_s0 = (g == 0) ? nnode : ncp[cidx(g, n_pmax)];
            n_i1 = ncp[cidx(g + EPW, n_pmax)];
            n_i2 = ncp[cidx(g + 2 * EPW, n_pmax)];
            n_si3 = ncp[cidx(g + 3 * EPW, n_pmax)];
        }

        // ---- D: edge loop for node k (3-slot modulo schedule, R18) ----
        float denom = 0.f;
        f32x2 acc2[4] = {};
        int p = g;
        auto do_iter = [&](v8h& curv) {
            const h2* c2 = (const h2*)&curv;
            f32x2 a2[4];
#pragma unroll
            for (int j = 0; j < 4; ++j) { a2[j][0] = (float)c2[j][0]; a2[j][1] = (float)c2[j][1]; }
            curv = rowload(si3);             // slot free after cvt; depth-3 prefetch
            si3 = cp[cidx(p + 4 * EPW, pmax)];

            f32x2 sdot = {0.f, 0.f};
#pragma unroll
            for (int j = 0; j < 4; ++j) {
                f32x2 v = a2[j] + xr2[j];
                f32x2 vn = v * NEG_SLOPE;
                f32x2 lv;
                lv[0] = fmaxf(v[0], vn[0]); lv[1] = fmaxf(v[1], vn[1]);
                sdot += at2[j] * lv;
            }
            float s = sdot[0] + sdot[1];
            s = dpp_xadd<0xB1>(s);           // quad_perm [1,0,3,2]
            s = dpp_xadd<0x4E>(s);           // quad_perm [2,3,0,1]
            s = dpp_xadd<0x141>(s);          // row_half_mirror: i <-> 7-i within 8
            float f = exp2f(s);              // att pre-scaled by log2e
            denom += f;
            f32x2 f2 = {f, f};
#pragma unroll
            for (int j = 0; j < 4; ++j) acc2[j] += a2[j] * f2;   // v_pk_fma_f32
            p += EPW;
        };
        while (p < P) {
            do_iter(ah0);
            if (p >= P) break;
            do_iter(ah1);
            if (p >= P) break;
            do_iter(ah2);
        }

        // ---- E: issue row loads for node k+1 (indices from C returned during D) ----
        if (has_next) {
            ah0 = rowload(n_s0);
            ah1 = rowload(n_i1);
            ah2 = rowload(n_i2);
        }

        // ---- F: epilogue for node k (hides part of E's row latency) ----
#pragma unroll
        for (int o = LPE; o < 64; o <<= 1) {
#pragma unroll
            for (int j = 0; j < 4; ++j) {
                acc2[j][0] += __shfl_xor(acc2[j][0], o);
                acc2[j][1] += __shfl_xor(acc2[j][1], o);
            }
            denom += __shfl_xor(denom, o);
        }
        if (lane < LPE) {
            float inv = __builtin_amdgcn_rcpf(denom);   // approx rcp, once per node
            OUT_T* orow = out + (size_t)node * HOUT + cb;
#pragma unroll
            for (int j = 0; j < 4; ++j) {
#pragma unroll
                for (int t = 0; t < 2; ++t) {
                    float r = acc2[j][t] * inv + bias[cb + 2 * j + t];
                    r = r > 0.f ? r : (__expf(r) - 1.f);    // elu via fast exp
                    orow[2 * j + t] = (OUT_T)r;
                }
            }
        }
        if (!has_next) return;

        // ---- G: rotate pipeline state ----
        node = nnode; nnode = n2;
        eoff = n_eoff; eend = n_eend; xrh = n_xrh;
        P = eend - eoff + 1;
        cp = ncp; pmax = n_pmax; si3 = n_si3;
        n_eoff = a_eoff; n_eend = a_eend; n_xrh = a_xrh;
    }
}

extern "C" void kernel_launch(void* const* d_in, const int* in_sizes, int n_in,
                              void* d_out, int out_size, void* d_ws, size_t ws_size,
                              hipStream_t stream) {
    const float* x    = (const float*)d_in[0];
    const int*   ei   = (const int*)d_in[1];
    const int*   esrc = ei;
    const int*   edst = ei + N_EDGES;
    const float* W1l = (const float*)d_in[2];
    const float* W1r = (const float*)d_in[3];
    const float* att1= (const float*)d_in[4];
    const float* b1  = (const float*)d_in[5];
    const float* W2l = (const float*)d_in[6];
    const float* W2r = (const float*)d_in[7];
    const float* att2= (const float*)d_in[8];
    const float* b2  = (const float*)d_in[9];
    const float* W3l = (const float*)d_in[10];
    const float* W3r = (const float*)d_in[11];
    const float* att3= (const float*)d_in[12];
    const float* b3  = (const float*)d_in[13];
    float* out = (float*)d_out;

    // ---- workspace layout ----
    _Float16* XLR = (_Float16*)d_ws;                    // 50000*256
    _Float16* Hb  = XLR + (size_t)N_NODES * 256;        // 50000*128
    _Float16* Wt1 = Hb + (size_t)N_NODES * 128;         // 256*128
    _Float16* Wt2 = Wt1 + 256 * 128;                    // 256*128
    _Float16* Wt3 = Wt2 + 256 * 128;                    // 128*128
    int* bcnt = (int*)(Wt3 + 128 * 128);                // 512
    int* off  = bcnt + N_BKT;                           // 50001 (+1 pad)
    int* csr  = off + N_NODES + 1 + 1;                  // 800000
    int2* tmp = (int2*)(csr + N_EDGES);                 // N_BKT*BCAP int2 = 16.8 MB

    const int TB = 256;

    // ---- CSR build + weight prep; layer-1 GEMM merged with CSR finalize ----
    pack_weights_zero<<<cdiv(81920 + N_BKT, TB), TB, 0, stream>>>(
        W1l, W1r, W2l, W2r, W3l, W3r, Wt1, Wt2, Wt3, bcnt);
    bucket_scatter<<<cdiv(N_EDGES, CHUNK), 512, 0, stream>>>(esrc, edst, bcnt, tmp);
    csr_and_gemm1<<<NB_CSR + G1_BLOCKS, 256, 0, stream>>>(bcnt, tmp, off, csr, x, Wt1, XLR);

    // R19: persistent gat grid — 3072 blocks x 2 waves = 6144 waves (full residency at
    // 6 waves/EU), each wave pipelines ~8 nodes.
    const int GAT_BLOCKS = 3072;
    dim3 g2(cdiv(N_NODES, 128) * 2), g1(cdiv(N_NODES, 128));

    // ---- layer 1 ----
    fused_gat<128, _Float16><<<GAT_BLOCKS, 128, 0, stream>>>(XLR, off, csr, att1, b1, Hb);
    // ---- layer 2 ----
    gemm_xlr<256><<<g2, 256, 0, stream>>>(Hb, Wt2, XLR);
    fused_gat<128, _Float16><<<GAT_BLOCKS, 128, 0, stream>>>(XLR, off, csr, att2, b2, Hb);
    // ---- layer 3 ----
    gemm_xlr<128><<<g1, 256, 0, stream>>>(Hb, Wt3, XLR);
    fused_gat<64, float><<<GAT_BLOCKS, 128, 0, stream>>>(XLR, off, csr, att3, b3, out);
}

// Round 6
// 315.698 us; speedup vs baseline: 1.3481x; 1.3481x over previous
//
#include <hip/hip_runtime.h>
#include <hip/hip_fp16.h>
#include <math.h>

#define N_NODES 50000
#define N_EDGES 800000
#define NEG_SLOPE 0.2f

#define BKT_SHIFT 7
#define N_BKT 512                      // pow2 upper bound; used: ceil(50000/128)=391
#define NB_CSR ((N_NODES + 127) / 128) // 391
#define CHUNK 2048                     // edges per phase-A block
#define BCAP 4096                      // fixed bucket capacity (mean 2048, 45 sigma)
#define PB_CAP 4096
#define G1_BLOCKS (((N_NODES + 127) / 128) * 2)   // 782 gemm-1 blocks (2 n-tiles)

typedef _Float16 v8h __attribute__((ext_vector_type(8)));
typedef _Float16 h4  __attribute__((ext_vector_type(4)));
typedef _Float16 h2  __attribute__((ext_vector_type(2)));
typedef float f32x4 __attribute__((ext_vector_type(4)));
typedef float f32x2 __attribute__((ext_vector_type(2)));

static inline int cdiv(long long a, int b) { return (int)((a + b - 1) / b); }

// DPP-fused butterfly add step (VALU add reading neighbor via DPP, no LDS).
// CTRL: 0xB1 = quad_perm[1,0,3,2] (xor1), 0x4E = quad_perm[2,3,0,1] (xor2),
// 0x141 = row_half_mirror (lane i <-> 7-i within each 8-lane half).
template<int CTRL>
static __device__ __forceinline__ float dpp_xadd(float s) {
    int t = __builtin_amdgcn_mov_dpp(__builtin_bit_cast(int, s), CTRL, 0xf, 0xf, true);
    return s + __builtin_bit_cast(float, t);
}

// ========= weight packing W[K][N] f32 -> Wt[N][K] f16, plus bcnt zero-init =========
__global__ void pack_weights_zero(const float* __restrict__ W1l, const float* __restrict__ W1r,
                                  const float* __restrict__ W2l, const float* __restrict__ W2r,
                                  const float* __restrict__ W3l, const float* __restrict__ W3r,
                                  _Float16* __restrict__ Wt1, _Float16* __restrict__ Wt2,
                                  _Float16* __restrict__ Wt3, int* __restrict__ bcnt) {
    int id = blockIdx.x * blockDim.x + threadIdx.x;
    if (id < 32768) {                       // Wt1: [256][128]
        int n = id >> 7, k = id & 127;
        Wt1[id] = (_Float16)(n < 128 ? W1l[k * 128 + n] : W1r[k * 128 + n - 128]);
    } else if (id < 65536) {                // Wt2: [256][128]
        int j = id - 32768; int n = j >> 7, k = j & 127;
        Wt2[j] = (_Float16)(n < 128 ? W2l[k * 128 + n] : W2r[k * 128 + n - 128]);
    } else if (id < 81920) {                // Wt3: [128][128]
        int j = id - 65536; int n = j >> 7, k = j & 127;
        Wt3[j] = (_Float16)(n < 64 ? W3l[k * 64 + n] : W3r[k * 64 + n - 64]);
    } else if (id < 81920 + N_BKT) {
        bcnt[id - 81920] = 0;
    }
}

// ===== Phase A: LDS bucket sort per 2048-edge chunk, coalesced run append =====
__global__ __launch_bounds__(512) void bucket_scatter(const int* __restrict__ esrc,
                                                      const int* __restrict__ edst,
                                                      int* __restrict__ bcnt,
                                                      int2* __restrict__ tmp) {
    __shared__ int lhist[N_BKT];
    __shared__ int lscan[N_BKT];
    __shared__ int lofs[N_BKT];
    __shared__ int lcur[N_BKT];
    __shared__ int gbase[N_BKT];
    __shared__ int2 lpair[CHUNK];
    int tid = threadIdx.x;
    int base_e = blockIdx.x * CHUNK;
    int count = min(CHUNK, N_EDGES - base_e);

    if (tid < N_BKT) lhist[tid] = 0;
    __syncthreads();

    int e0 = base_e + tid * 4;
    int4 s4 = {0, 0, 0, 0}, d4 = {0, 0, 0, 0};
    int nmine = 0;
    if (e0 + 3 < N_EDGES && e0 + 3 < base_e + count) {
        s4 = *(const int4*)(esrc + e0);
        d4 = *(const int4*)(edst + e0);
        nmine = 4;
    } else if (e0 < N_EDGES) {
        nmine = min(N_EDGES - e0, 4);
        const int* sp = esrc + e0;
        const int* dp = edst + e0;
        if (nmine > 0) { s4.x = sp[0]; d4.x = dp[0]; }
        if (nmine > 1) { s4.y = sp[1]; d4.y = dp[1]; }
        if (nmine > 2) { s4.z = sp[2]; d4.z = dp[2]; }
    }
    int ds[4] = {d4.x, d4.y, d4.z, d4.w};
    int ss[4] = {s4.x, s4.y, s4.z, s4.w};
#pragma unroll
    for (int u = 0; u < 4; ++u)
        if (u < nmine) atomicAdd(&lhist[ds[u] >> BKT_SHIFT], 1);
    __syncthreads();

    // exclusive scan over N_BKT in LDS (Hillis-Steele, 512 threads = N_BKT)
    int v = lhist[tid];
    lscan[tid] = v;
    __syncthreads();
    for (int st = 1; st < N_BKT; st <<= 1) {
        int t = (tid >= st) ? lscan[tid - st] : 0;
        __syncthreads();
        lscan[tid] += t;
        __syncthreads();
    }
    {
        int excl = lscan[tid] - v;
        lofs[tid] = excl;
        lcur[tid] = excl;
        if (v > 0) gbase[tid] = tid * BCAP + atomicAdd(&bcnt[tid], v);
    }
    __syncthreads();

#pragma unroll
    for (int u = 0; u < 4; ++u)
        if (u < nmine) {
            int b = ds[u] >> BKT_SHIFT;
            int p = atomicAdd(&lcur[b], 1);
            lpair[p] = make_int2(ss[u], ds[u]);
        }
    __syncthreads();

    for (int j = tid; j < count; j += 512) {
        int2 pr = lpair[j];
        int b = pr.y >> BKT_SHIFT;
        int idx = gbase[b] + (j - lofs[b]);
        if (idx < (b + 1) * BCAP) tmp[idx] = pr;   // 45-sigma overflow guard
    }
}

// ===== Merged dispatch: blocks [0,391) finalize CSR; blocks [391, 391+782) run layer-1 GEMM =====
// R15: n-tile (by) fastest-varying so both n-tiles of a bx run temporally adjacent -> the
// f32 A rows (25.6MB) are read once from HBM, second read hits L2/L3.
__global__ __launch_bounds__(256, 2) void csr_and_gemm1(const int* __restrict__ bcnt,
                                                        const int2* __restrict__ tmp,
                                                        int* __restrict__ off,
                                                        int* __restrict__ csr,
                                                        const float* __restrict__ A,
                                                        const _Float16* __restrict__ Bt,
                                                        _Float16* __restrict__ C) {
    __shared__ int red[256];
    __shared__ int lcnt[128];
    __shared__ int sc[128];
    __shared__ int loff[129];
    __shared__ int lcur[128];
    __shared__ int lcsr[PB_CAP];
    int tid = threadIdx.x;

    if (blockIdx.x >= NB_CSR) {
        // ---------------- layer-1 GEMM part (A = f32 input, cast in-register) ------------
        int gb = blockIdx.x - NB_CSR;
        int bx = gb >> 1;               // R15: by fastest for A-row temporal reuse
        int by = gb & 1;                // 0 or 1
        int w = tid >> 6, lane = tid & 63;
        int m0 = bx * 128 + (w & 1) * 64;
        int n0 = by * 128 + (w >> 1) * 64;
        int q = lane >> 4, li = lane & 15;
        f32x4 acc[4][4] = {};
        const float* Ap[4];
#pragma unroll
        for (int a = 0; a < 4; ++a) {
            int row = m0 + 16 * a + li;
            if (row > N_NODES - 1) row = N_NODES - 1;
            Ap[a] = A + (size_t)row * 128 + q * 8;
        }
        const _Float16* Bp = Bt + (size_t)(n0 + li) * 128 + q * 8;
#pragma unroll
        for (int kt = 0; kt < 4; ++kt) {
            v8h af[4], bf[4];
#pragma unroll
            for (int a = 0; a < 4; ++a) {
                float4 lo = *(const float4*)(Ap[a] + kt * 32);
                float4 hi = *(const float4*)(Ap[a] + kt * 32 + 4);
                v8h t;
                t[0] = (_Float16)lo.x; t[1] = (_Float16)lo.y; t[2] = (_Float16)lo.z; t[3] = (_Float16)lo.w;
                t[4] = (_Float16)hi.x; t[5] = (_Float16)hi.y; t[6] = (_Float16)hi.z; t[7] = (_Float16)hi.w;
                af[a] = t;
            }
#pragma unroll
            for (int b = 0; b < 4; ++b) bf[b] = *(const v8h*)(Bp + (size_t)(16 * b) * 128 + kt * 32);
#pragma unroll
            for (int a = 0; a < 4; ++a)
#pragma unroll
                for (int b = 0; b < 4; ++b)
                    acc[a][b] = __builtin_amdgcn_mfma_f32_16x16x32_f16(bf[b], af[a], acc[a][b], 0, 0, 0);
        }
#pragma unroll
        for (int a = 0; a < 4; ++a) {
            int m = m0 + 16 * a + li;
            if (m < N_NODES) {
#pragma unroll
                for (int b = 0; b < 4; ++b) {
                    h4 t;
                    t[0] = (_Float16)acc[a][b][0]; t[1] = (_Float16)acc[a][b][1];
                    t[2] = (_Float16)acc[a][b][2]; t[3] = (_Float16)acc[a][b][3];
                    *(h4*)(C + (size_t)m * 256 + n0 + 16 * b + 4 * q) = t;
                }
            }
        }
        return;
    }

    // ---------------- CSR finalize part ----------------
    int b = blockIdx.x;
    int d0 = b << BKT_SHIFT;
    int dend = min(d0 + 128, N_NODES);
    int nn = dend - d0;

    int pre = 0;
    for (int i = tid; i < b; i += 256) pre += bcnt[i];
    red[tid] = pre;
    __syncthreads();
    for (int st = 128; st > 0; st >>= 1) {
        if (tid < st) red[tid] += red[tid + st];
        __syncthreads();
    }
    int base = red[0];
    __syncthreads();

    int n = min(bcnt[b], BCAP);
    int tbase = b * BCAP;

    if (tid < 128) lcnt[tid] = 0;
    __syncthreads();
    for (int j = tid; j < n; j += 256) {
        int dl = tmp[tbase + j].y - d0;
        atomicAdd(&lcnt[dl], 1);
    }
    __syncthreads();

    if (tid < 128) sc[tid] = lcnt[tid];
    __syncthreads();
    for (int st = 1; st < 128; st <<= 1) {
        int t = (tid < 128 && tid >= st) ? sc[tid - st] : 0;
        __syncthreads();
        if (tid < 128) sc[tid] += t;
        __syncthreads();
    }
    if (tid < 128) loff[tid + 1] = sc[tid];
    if (tid == 0) loff[0] = 0;
    if (tid < 128) lcur[tid] = 0;
    __syncthreads();

    if (tid < nn) off[d0 + tid] = base + loff[tid];
    if (tid == 0 && dend == N_NODES) off[N_NODES] = base + loff[nn];

    for (int j = tid; j < n; j += 256) {
        int2 pr = tmp[tbase + j];
        int dl = pr.y - d0;
        int r = atomicAdd(&lcur[dl], 1);
        int pos = loff[dl] + r;
        if (pos < PB_CAP) lcsr[pos] = pr.x;
    }
    __syncthreads();
    for (int j = tid; j < n; j += 256) csr[base + j] = lcsr[j];
}

// ===== MFMA GEMM (layers 2,3): C[M][NT](f16) = A[M][128] @ Bt[NT][128]^T =====
// R15: 1-D grid, n-tile fastest -> both n-tiles of a bx temporally adjacent (A reuse in L2/L3).
// R19: launch_bounds 3 (proven config; 4 risked VGPR cap spill).
template<int NT>
__global__ __launch_bounds__(256, 3) void gemm_xlr(const _Float16* __restrict__ A,
                                                   const _Float16* __restrict__ Bt,
                                                   _Float16* __restrict__ C) {
    constexpr int NY = NT / 128;
    int bx = blockIdx.x / NY;
    int by = blockIdx.x % NY;
    int w = threadIdx.x >> 6, lane = threadIdx.x & 63;
    int m0 = bx * 128 + (w & 1) * 64;
    int n0 = by * 128 + (w >> 1) * 64;
    int q = lane >> 4, li = lane & 15;
    f32x4 acc[4][4] = {};
    const _Float16* Ap[4];
#pragma unroll
    for (int a = 0; a < 4; ++a) {
        int row = m0 + 16 * a + li;
        if (row > N_NODES - 1) row = N_NODES - 1;  // clamp: no OOB reads
        Ap[a] = A + (size_t)row * 128 + q * 8;
    }
    const _Float16* Bp = Bt + (size_t)(n0 + li) * 128 + q * 8;
#pragma unroll
    for (int kt = 0; kt < 4; ++kt) {
        v8h af[4], bf[4];
#pragma unroll
        for (int a = 0; a < 4; ++a) af[a] = *(const v8h*)(Ap[a] + kt * 32);
#pragma unroll
        for (int b = 0; b < 4; ++b) bf[b] = *(const v8h*)(Bp + (size_t)(16 * b) * 128 + kt * 32);
#pragma unroll
        for (int a = 0; a < 4; ++a)
#pragma unroll
            for (int b = 0; b < 4; ++b)
                acc[a][b] = __builtin_amdgcn_mfma_f32_16x16x32_f16(bf[b], af[a], acc[a][b], 0, 0, 0);
    }
#pragma unroll
    for (int a = 0; a < 4; ++a) {
        int m = m0 + 16 * a + li;
        if (m < N_NODES) {
#pragma unroll
            for (int b = 0; b < 4; ++b) {
                h4 t;
                t[0] = (_Float16)acc[a][b][0]; t[1] = (_Float16)acc[a][b][1];
                t[2] = (_Float16)acc[a][b][2]; t[3] = (_Float16)acc[a][b][3];
                *(h4*)(C + (size_t)m * NT + n0 + 16 * b + 4 * q) = t;
            }
        }
    }
}

// ========== fused GATv2: persistent waves, 2-ahead cross-NODE software pipeline ==========
// R19 REGRESSED but was confounded: __launch_bounds__(128,6) capped VGPR at ~85, compiler
// allocated 40 and SPILLED the pipeline state (WRITE_SIZE 12.5->188MB = scratch traffic,
// VALUBusy 35%). The pipeline mechanism was never tested. R20: __launch_bounds__(128,4)
// -> 128-VGPR cap, state (~90-100) fits, no spill. 4 waves/EU x 16 waves/CU of PIPELINED
// waves (exposed chain ~300cyc) vs R18's 20 waves unpipelined (~1300cyc exposed).
// Pre-commit: if WRITE back at 12.5MB + VGPR>=96 and gat still >=43us -> pipeline
// falsified, revert to R18 next round.
template<int HOUT, typename OUT_T>
__global__ __launch_bounds__(128, 4) void fused_gat(
    const _Float16* __restrict__ XLR,   // [N][2*HOUT] = [xl | xr]
    const int* __restrict__ off, const int* __restrict__ csr,
    const float* __restrict__ att, const float* __restrict__ bias,
    OUT_T* __restrict__ out) {          // [N][HOUT]
    constexpr int VEC = 8;
    constexpr int LPE = HOUT / VEC;     // lanes per edge (16 or 8)
    constexpr int EPW = 64 / LPE;       // edge groups per wave (4 or 8)
    constexpr int ST = 2 * HOUT;
    int wave = threadIdx.x >> 6, lane = threadIdx.x & 63;
    int wid = blockIdx.x * (blockDim.x >> 6) + wave;
    int NW = gridDim.x * (blockDim.x >> 6);
    int g = lane / LPE;
    int lg = lane % LPE;
    int cb = lg * VEC;

    constexpr float LOG2E = 1.44269504088896340736f;
    f32x2 at2[4];
#pragma unroll
    for (int j = 0; j < 4; ++j) {
        at2[j][0] = att[cb + 2 * j] * LOG2E;       // fold log2e -> exp2 domain
        at2[j][1] = att[cb + 2 * j + 1] * LOG2E;
    }

    const _Float16* Xcb = XLR + cb;

    // clamped csr index for position pos (pos >= 1): clamp(pos-1, 0, pm)
    auto cidx = [](int pos, int pm) -> int {
        int i = pos - 1;
        i = i > pm ? pm : i;
        return i < 0 ? 0 : i;
    };
    // clamped row load (src index garbage-safe)
    auto rowload = [&](int s) -> v8h {
        s = s < 0 ? 0 : s;
        s = s > N_NODES - 1 ? N_NODES - 1 : s;
        return *(const v8h*)(Xcb + (size_t)s * ST);
    };

    int node = wid;
    if (node >= N_NODES) return;

    // ---- cold prologue for first node ----
    int eoff = off[node], eend = off[node + 1];
    v8h xrh = *(const v8h*)(XLR + (size_t)node * ST + HOUT + cb);
    int P = eend - eoff + 1;            // position 0 = self-loop, 1..deg = csr edges
    const int* cp = csr + eoff;
    int pmax = P - 2;
    int si3 = cp[cidx(g + 3 * EPW, pmax)];
    int s0c = (g == 0) ? node : cp[cidx(g, pmax)];
    v8h ah0 = rowload(s0c);
    v8h ah1 = rowload(cp[cidx(g + EPW, pmax)]);
    v8h ah2 = rowload(cp[cidx(g + 2 * EPW, pmax)]);

    // next-node off/xr prefetch (1-ahead)
    int nnode = node + NW;
    int n_eoff = 0, n_eend = 0;
    v8h n_xrh = {};
    if (nnode < N_NODES) {
        n_eoff = off[nnode]; n_eend = off[nnode + 1];
        n_xrh = *(const v8h*)(XLR + (size_t)nnode * ST + HOUT + cb);
    }

    while (true) {
        // ---- A: issue 2-ahead off/xr for node k+2 ----
        int n2 = node + 2 * NW;
        int a_eoff = 0, a_eend = 0;
        v8h a_xrh = {};
        if (n2 < N_NODES) {
            a_eoff = off[n2]; a_eend = off[n2 + 1];
            a_xrh = *(const v8h*)(XLR + (size_t)n2 * ST + HOUT + cb);
        }

        // ---- B: convert current xr (xrh issued >= 1 node ago -> ready) ----
        f32x2 xr2[4];
        {
            const h2* x2 = (const h2*)&xrh;
#pragma unroll
            for (int j = 0; j < 4; ++j) { xr2[j][0] = (float)x2[j][0]; xr2[j][1] = (float)x2[j][1]; }
        }

        // ---- C: issue csr-idx prologue for node k+1 (n_eoff ready) ----
        bool has_next = nnode < N_NODES;
        int n_pmax = 0, n_si3 = 0, n_s0 = 0, n_i1 = 0, n_i2 = 0;
        const int* ncp = nullptr;
        if (has_next) {
            int nP = n_eend - n_eoff + 1;
            ncp = csr + n_eoff;
            n_pmax = nP - 2;
            n_s0 = (g == 0) ? nnode : ncp[cidx(g, n_pmax)];
            n_i1 = ncp[cidx(g + EPW, n_pmax)];
            n_i2 = ncp[cidx(g + 2 * EPW, n_pmax)];
            n_si3 = ncp[cidx(g + 3 * EPW, n_pmax)];
        }

        // ---- D: edge loop for node k (3-slot modulo schedule, R18) ----
        float denom = 0.f;
        f32x2 acc2[4] = {};
        int p = g;
        auto do_iter = [&](v8h& curv) {
            const h2* c2 = (const h2*)&curv;
            f32x2 a2[4];
#pragma unroll
            for (int j = 0; j < 4; ++j) { a2[j][0] = (float)c2[j][0]; a2[j][1] = (float)c2[j][1]; }
            curv = rowload(si3);             // slot free after cvt; depth-3 prefetch
            si3 = cp[cidx(p + 4 * EPW, pmax)];

            f32x2 sdot = {0.f, 0.f};
#pragma unroll
            for (int j = 0; j < 4; ++j) {
                f32x2 v = a2[j] + xr2[j];
                f32x2 vn = v * NEG_SLOPE;
                f32x2 lv;
                lv[0] = fmaxf(v[0], vn[0]); lv[1] = fmaxf(v[1], vn[1]);
                sdot += at2[j] * lv;
            }
            float s = sdot[0] + sdot[1];
            s = dpp_xadd<0xB1>(s);           // quad_perm [1,0,3,2]
            s = dpp_xadd<0x4E>(s);           // quad_perm [2,3,0,1]
            s = dpp_xadd<0x141>(s);          // row_half_mirror: i <-> 7-i within 8
            float f = exp2f(s);              // att pre-scaled by log2e
            denom += f;
            f32x2 f2 = {f, f};
#pragma unroll
            for (int j = 0; j < 4; ++j) acc2[j] += a2[j] * f2;   // v_pk_fma_f32
            p += EPW;
        };
        while (p < P) {
            do_iter(ah0);
            if (p >= P) break;
            do_iter(ah1);
            if (p >= P) break;
            do_iter(ah2);
        }

        // ---- E: issue row loads for node k+1 (indices from C returned during D) ----
        if (has_next) {
            ah0 = rowload(n_s0);
            ah1 = rowload(n_i1);
            ah2 = rowload(n_i2);
        }

        // ---- F: epilogue for node k (hides part of E's row latency) ----
#pragma unroll
        for (int o = LPE; o < 64; o <<= 1) {
#pragma unroll
            for (int j = 0; j < 4; ++j) {
                acc2[j][0] += __shfl_xor(acc2[j][0], o);
                acc2[j][1] += __shfl_xor(acc2[j][1], o);
            }
            denom += __shfl_xor(denom, o);
        }
        if (lane < LPE) {
            float inv = __builtin_amdgcn_rcpf(denom);   // approx rcp, once per node
            OUT_T* orow = out + (size_t)node * HOUT + cb;
#pragma unroll
            for (int j = 0; j < 4; ++j) {
#pragma unroll
                for (int t = 0; t < 2; ++t) {
                    float r = acc2[j][t] * inv + bias[cb + 2 * j + t];
                    r = r > 0.f ? r : (__expf(r) - 1.f);    // elu via fast exp
                    orow[2 * j + t] = (OUT_T)r;
                }
            }
        }
        if (!has_next) return;

        // ---- G: rotate pipeline state ----
        node = nnode; nnode = n2;
        eoff = n_eoff; eend = n_eend; xrh = n_xrh;
        P = eend - eoff + 1;
        cp = ncp; pmax = n_pmax; si3 = n_si3;
        n_eoff = a_eoff; n_eend = a_eend; n_xrh = a_xrh;
    }
}

extern "C" void kernel_launch(void* const* d_in, const int* in_sizes, int n_in,
                              void* d_out, int out_size, void* d_ws, size_t ws_size,
                              hipStream_t stream) {
    const float* x    = (const float*)d_in[0];
    const int*   ei   = (const int*)d_in[1];
    const int*   esrc = ei;
    const int*   edst = ei + N_EDGES;
    const float* W1l = (const float*)d_in[2];
    const float* W1r = (const float*)d_in[3];
    const float* att1= (const float*)d_in[4];
    const float* b1  = (const float*)d_in[5];
    const float* W2l = (const float*)d_in[6];
    const float* W2r = (const float*)d_in[7];
    const float* att2= (const float*)d_in[8];
    const float* b2  = (const float*)d_in[9];
    const float* W3l = (const float*)d_in[10];
    const float* W3r = (const float*)d_in[11];
    const float* att3= (const float*)d_in[12];
    const float* b3  = (const float*)d_in[13];
    float* out = (float*)d_out;

    // ---- workspace layout ----
    _Float16* XLR = (_Float16*)d_ws;                    // 50000*256
    _Float16* Hb  = XLR + (size_t)N_NODES * 256;        // 50000*128
    _Float16* Wt1 = Hb + (size_t)N_NODES * 128;         // 256*128
    _Float16* Wt2 = Wt1 + 256 * 128;                    // 256*128
    _Float16* Wt3 = Wt2 + 256 * 128;                    // 128*128
    int* bcnt = (int*)(Wt3 + 128 * 128);                // 512
    int* off  = bcnt + N_BKT;                           // 50001 (+1 pad)
    int* csr  = off + N_NODES + 1 + 1;                  // 800000
    int2* tmp = (int2*)(csr + N_EDGES);                 // N_BKT*BCAP int2 = 16.8 MB

    const int TB = 256;

    // ---- CSR build + weight prep; layer-1 GEMM merged with CSR finalize ----
    pack_weights_zero<<<cdiv(81920 + N_BKT, TB), TB, 0, stream>>>(
        W1l, W1r, W2l, W2r, W3l, W3r, Wt1, Wt2, Wt3, bcnt);
    bucket_scatter<<<cdiv(N_EDGES, CHUNK), 512, 0, stream>>>(esrc, edst, bcnt, tmp);
    csr_and_gemm1<<<NB_CSR + G1_BLOCKS, 256, 0, stream>>>(bcnt, tmp, off, csr, x, Wt1, XLR);

    // R20: persistent gat grid sized to exact residency at 4 waves/EU:
    // 2048 blocks x 2 waves = 4096 waves = 16/CU; each wave pipelines ~12 nodes.
    const int GAT_BLOCKS = 2048;
    dim3 g2(cdiv(N_NODES, 128) * 2), g1(cdiv(N_NODES, 128));

    // ---- layer 1 ----
    fused_gat<128, _Float16><<<GAT_BLOCKS, 128, 0, stream>>>(XLR, off, csr, att1, b1, Hb);
    // ---- layer 2 ----
    gemm_xlr<256><<<g2, 256, 0, stream>>>(Hb, Wt2, XLR);
    fused_gat<128, _Float16><<<GAT_BLOCKS, 128, 0, stream>>>(XLR, off, csr, att2, b2, Hb);
    // ---- layer 3 ----
    gemm_xlr<128><<<g1, 256, 0, stream>>>(Hb, Wt3, XLR);
    fused_gat<64, float><<<GAT_BLOCKS, 128, 0, stream>>>(XLR, off, csr, att3, b3, out);
}

// Round 7
// 290.342 us; speedup vs baseline: 1.4658x; 1.0873x over previous
//
#include <hip/hip_runtime.h>
#include <hip/hip_fp16.h>
#include <math.h>

#define N_NODES 50000
#define N_EDGES 800000
#define NEG_SLOPE 0.2f

#define BKT_SHIFT 7
#define N_BKT 512                      // pow2 upper bound; used: ceil(50000/128)=391
#define NB_CSR ((N_NODES + 127) / 128) // 391
#define CHUNK 2048                     // edges per phase-A block
#define BCAP 4096                      // fixed bucket capacity (mean 2048, 45 sigma)
#define PB_CAP 4096
#define G1_BLOCKS (((N_NODES + 127) / 128) * 2)   // 782 gemm-1 blocks (2 n-tiles)

typedef _Float16 v8h __attribute__((ext_vector_type(8)));
typedef _Float16 h4  __attribute__((ext_vector_type(4)));
typedef _Float16 h2  __attribute__((ext_vector_type(2)));
typedef float f32x4 __attribute__((ext_vector_type(4)));
typedef float f32x2 __attribute__((ext_vector_type(2)));

static inline int cdiv(long long a, int b) { return (int)((a + b - 1) / b); }

// DPP-fused butterfly add step (VALU add reading neighbor via DPP, no LDS).
// CTRL: 0xB1 = quad_perm[1,0,3,2] (xor1), 0x4E = quad_perm[2,3,0,1] (xor2),
// 0x141 = row_half_mirror (lane i <-> 7-i within each 8-lane half).
template<int CTRL>
static __device__ __forceinline__ float dpp_xadd(float s) {
    int t = __builtin_amdgcn_mov_dpp(__builtin_bit_cast(int, s), CTRL, 0xf, 0xf, true);
    return s + __builtin_bit_cast(float, t);
}

// ========= weight packing W[K][N] f32 -> Wt[N][K] f16, plus bcnt zero-init =========
__global__ void pack_weights_zero(const float* __restrict__ W1l, const float* __restrict__ W1r,
                                  const float* __restrict__ W2l, const float* __restrict__ W2r,
                                  const float* __restrict__ W3l, const float* __restrict__ W3r,
                                  _Float16* __restrict__ Wt1, _Float16* __restrict__ Wt2,
                                  _Float16* __restrict__ Wt3, int* __restrict__ bcnt) {
    int id = blockIdx.x * blockDim.x + threadIdx.x;
    if (id < 32768) {                       // Wt1: [256][128]
        int n = id >> 7, k = id & 127;
        Wt1[id] = (_Float16)(n < 128 ? W1l[k * 128 + n] : W1r[k * 128 + n - 128]);
    } else if (id < 65536) {                // Wt2: [256][128]
        int j = id - 32768; int n = j >> 7, k = j & 127;
        Wt2[j] = (_Float16)(n < 128 ? W2l[k * 128 + n] : W2r[k * 128 + n - 128]);
    } else if (id < 81920) {                // Wt3: [128][128]
        int j = id - 65536; int n = j >> 7, k = j & 127;
        Wt3[j] = (_Float16)(n < 64 ? W3l[k * 64 + n] : W3r[k * 64 + n - 64]);
    } else if (id < 81920 + N_BKT) {
        bcnt[id - 81920] = 0;
    }
}

// ===== Phase A: LDS bucket sort per 2048-edge chunk, coalesced run append =====
__global__ __launch_bounds__(512) void bucket_scatter(const int* __restrict__ esrc,
                                                      const int* __restrict__ edst,
                                                      int* __restrict__ bcnt,
                                                      int2* __restrict__ tmp) {
    __shared__ int lhist[N_BKT];
    __shared__ int lscan[N_BKT];
    __shared__ int lofs[N_BKT];
    __shared__ int lcur[N_BKT];
    __shared__ int gbase[N_BKT];
    __shared__ int2 lpair[CHUNK];
    int tid = threadIdx.x;
    int base_e = blockIdx.x * CHUNK;
    int count = min(CHUNK, N_EDGES - base_e);

    if (tid < N_BKT) lhist[tid] = 0;
    __syncthreads();

    int e0 = base_e + tid * 4;
    int4 s4 = {0, 0, 0, 0}, d4 = {0, 0, 0, 0};
    int nmine = 0;
    if (e0 + 3 < N_EDGES && e0 + 3 < base_e + count) {
        s4 = *(const int4*)(esrc + e0);
        d4 = *(const int4*)(edst + e0);
        nmine = 4;
    } else if (e0 < N_EDGES) {
        nmine = min(N_EDGES - e0, 4);
        const int* sp = esrc + e0;
        const int* dp = edst + e0;
        if (nmine > 0) { s4.x = sp[0]; d4.x = dp[0]; }
        if (nmine > 1) { s4.y = sp[1]; d4.y = dp[1]; }
        if (nmine > 2) { s4.z = sp[2]; d4.z = dp[2]; }
    }
    int ds[4] = {d4.x, d4.y, d4.z, d4.w};
    int ss[4] = {s4.x, s4.y, s4.z, s4.w};
#pragma unroll
    for (int u = 0; u < 4; ++u)
        if (u < nmine) atomicAdd(&lhist[ds[u] >> BKT_SHIFT], 1);
    __syncthreads();

    // exclusive scan over N_BKT in LDS (Hillis-Steele, 512 threads = N_BKT)
    int v = lhist[tid];
    lscan[tid] = v;
    __syncthreads();
    for (int st = 1; st < N_BKT; st <<= 1) {
        int t = (tid >= st) ? lscan[tid - st] : 0;
        __syncthreads();
        lscan[tid] += t;
        __syncthreads();
    }
    {
        int excl = lscan[tid] - v;
        lofs[tid] = excl;
        lcur[tid] = excl;
        if (v > 0) gbase[tid] = tid * BCAP + atomicAdd(&bcnt[tid], v);
    }
    __syncthreads();

#pragma unroll
    for (int u = 0; u < 4; ++u)
        if (u < nmine) {
            int b = ds[u] >> BKT_SHIFT;
            int p = atomicAdd(&lcur[b], 1);
            lpair[p] = make_int2(ss[u], ds[u]);
        }
    __syncthreads();

    for (int j = tid; j < count; j += 512) {
        int2 pr = lpair[j];
        int b = pr.y >> BKT_SHIFT;
        int idx = gbase[b] + (j - lofs[b]);
        if (idx < (b + 1) * BCAP) tmp[idx] = pr;   // 45-sigma overflow guard
    }
}

// ===== Merged dispatch: blocks [0,391) finalize CSR; blocks [391, 391+782) run layer-1 GEMM =====
// R15: n-tile (by) fastest-varying so both n-tiles of a bx run temporally adjacent.
// R21: kt-rounds explicitly double-buffered (named reg sets, static indexing) so the
// 4 serial {load->MFMA} rounds overlap: load kt+1 issues before MFMA kt.
__global__ __launch_bounds__(256, 2) void csr_and_gemm1(const int* __restrict__ bcnt,
                                                        const int2* __restrict__ tmp,
                                                        int* __restrict__ off,
                                                        int* __restrict__ csr,
                                                        const float* __restrict__ A,
                                                        const _Float16* __restrict__ Bt,
                                                        _Float16* __restrict__ C) {
    __shared__ int red[256];
    __shared__ int lcnt[128];
    __shared__ int sc[128];
    __shared__ int loff[129];
    __shared__ int lcur[128];
    __shared__ int lcsr[PB_CAP];
    int tid = threadIdx.x;

    if (blockIdx.x >= NB_CSR) {
        // ---------------- layer-1 GEMM part (A = f32 input, cast in-register) ------------
        int gb = blockIdx.x - NB_CSR;
        int bx = gb >> 1;               // R15: by fastest for A-row temporal reuse
        int by = gb & 1;                // 0 or 1
        int w = tid >> 6, lane = tid & 63;
        int m0 = bx * 128 + (w & 1) * 64;
        int n0 = by * 128 + (w >> 1) * 64;
        int q = lane >> 4, li = lane & 15;
        f32x4 acc[4][4] = {};
        const float* Ap[4];
#pragma unroll
        for (int a = 0; a < 4; ++a) {
            int row = m0 + 16 * a + li;
            if (row > N_NODES - 1) row = N_NODES - 1;
            Ap[a] = A + (size_t)row * 128 + q * 8;
        }
        const _Float16* Bp = Bt + (size_t)(n0 + li) * 128 + q * 8;

        // R21: 2-deep kt pipeline. Named A/B sets; kt indices compile-time (unrolled).
        float4 loA[4], hiA[4], loB[4], hiB[4];
        v8h bfA[4], bfB[4];
#pragma unroll
        for (int a = 0; a < 4; ++a) { loA[a] = *(const float4*)(Ap[a]); hiA[a] = *(const float4*)(Ap[a] + 4); }
#pragma unroll
        for (int b = 0; b < 4; ++b) bfA[b] = *(const v8h*)(Bp + (size_t)(16 * b) * 128);
#pragma unroll
        for (int kt = 0; kt < 4; kt += 2) {
            if (kt + 1 < 4) {
#pragma unroll
                for (int a = 0; a < 4; ++a) {
                    loB[a] = *(const float4*)(Ap[a] + (kt + 1) * 32);
                    hiB[a] = *(const float4*)(Ap[a] + (kt + 1) * 32 + 4);
                }
#pragma unroll
                for (int b = 0; b < 4; ++b) bfB[b] = *(const v8h*)(Bp + (size_t)(16 * b) * 128 + (kt + 1) * 32);
            }
            {
                v8h af[4];
#pragma unroll
                for (int a = 0; a < 4; ++a) {
                    v8h t;
                    t[0] = (_Float16)loA[a].x; t[1] = (_Float16)loA[a].y; t[2] = (_Float16)loA[a].z; t[3] = (_Float16)loA[a].w;
                    t[4] = (_Float16)hiA[a].x; t[5] = (_Float16)hiA[a].y; t[6] = (_Float16)hiA[a].z; t[7] = (_Float16)hiA[a].w;
                    af[a] = t;
                }
#pragma unroll
                for (int a = 0; a < 4; ++a)
#pragma unroll
                    for (int b = 0; b < 4; ++b)
                        acc[a][b] = __builtin_amdgcn_mfma_f32_16x16x32_f16(bfA[b], af[a], acc[a][b], 0, 0, 0);
            }
            if (kt + 2 < 4) {
#pragma unroll
                for (int a = 0; a < 4; ++a) {
                    loA[a] = *(const float4*)(Ap[a] + (kt + 2) * 32);
                    hiA[a] = *(const float4*)(Ap[a] + (kt + 2) * 32 + 4);
                }
#pragma unroll
                for (int b = 0; b < 4; ++b) bfA[b] = *(const v8h*)(Bp + (size_t)(16 * b) * 128 + (kt + 2) * 32);
            }
            {
                v8h af[4];
#pragma unroll
                for (int a = 0; a < 4; ++a) {
                    v8h t;
                    t[0] = (_Float16)loB[a].x; t[1] = (_Float16)loB[a].y; t[2] = (_Float16)loB[a].z; t[3] = (_Float16)loB[a].w;
                    t[4] = (_Float16)hiB[a].x; t[5] = (_Float16)hiB[a].y; t[6] = (_Float16)hiB[a].z; t[7] = (_Float16)hiB[a].w;
                    af[a] = t;
                }
#pragma unroll
                for (int a = 0; a < 4; ++a)
#pragma unroll
                    for (int b = 0; b < 4; ++b)
                        acc[a][b] = __builtin_amdgcn_mfma_f32_16x16x32_f16(bfB[b], af[a], acc[a][b], 0, 0, 0);
            }
        }
#pragma unroll
        for (int a = 0; a < 4; ++a) {
            int m = m0 + 16 * a + li;
            if (m < N_NODES) {
#pragma unroll
                for (int b = 0; b < 4; ++b) {
                    h4 t;
                    t[0] = (_Float16)acc[a][b][0]; t[1] = (_Float16)acc[a][b][1];
                    t[2] = (_Float16)acc[a][b][2]; t[3] = (_Float16)acc[a][b][3];
                    *(h4*)(C + (size_t)m * 256 + n0 + 16 * b + 4 * q) = t;
                }
            }
        }
        return;
    }

    // ---------------- CSR finalize part ----------------
    int b = blockIdx.x;
    int d0 = b << BKT_SHIFT;
    int dend = min(d0 + 128, N_NODES);
    int nn = dend - d0;

    int pre = 0;
    for (int i = tid; i < b; i += 256) pre += bcnt[i];
    red[tid] = pre;
    __syncthreads();
    for (int st = 128; st > 0; st >>= 1) {
        if (tid < st) red[tid] += red[tid + st];
        __syncthreads();
    }
    int base = red[0];
    __syncthreads();

    int n = min(bcnt[b], BCAP);
    int tbase = b * BCAP;

    if (tid < 128) lcnt[tid] = 0;
    __syncthreads();
    for (int j = tid; j < n; j += 256) {
        int dl = tmp[tbase + j].y - d0;
        atomicAdd(&lcnt[dl], 1);
    }
    __syncthreads();

    if (tid < 128) sc[tid] = lcnt[tid];
    __syncthreads();
    for (int st = 1; st < 128; st <<= 1) {
        int t = (tid < 128 && tid >= st) ? sc[tid - st] : 0;
        __syncthreads();
        if (tid < 128) sc[tid] += t;
        __syncthreads();
    }
    if (tid < 128) loff[tid + 1] = sc[tid];
    if (tid == 0) loff[0] = 0;
    if (tid < 128) lcur[tid] = 0;
    __syncthreads();

    if (tid < nn) off[d0 + tid] = base + loff[tid];
    if (tid == 0 && dend == N_NODES) off[N_NODES] = base + loff[nn];

    for (int j = tid; j < n; j += 256) {
        int2 pr = tmp[tbase + j];
        int dl = pr.y - d0;
        int r = atomicAdd(&lcur[dl], 1);
        int pos = loff[dl] + r;
        if (pos < PB_CAP) lcsr[pos] = pr.x;
    }
    __syncthreads();
    for (int j = tid; j < n; j += 256) csr[base + j] = lcsr[j];
}

// ===== MFMA GEMM (layers 2,3): C[M][NT](f16) = A[M][128] @ Bt[NT][128]^T =====
// R15: 1-D grid, n-tile fastest (A reuse in L2/L3). R19: 3 waves/EU (proven).
// R21: kt-rounds explicitly double-buffered (named reg sets A/B, static indexing):
// load kt+1 issues before MFMA kt -> 4 serial L2-latency rounds collapse to ~1 exposed.
// VGPR ~140 < 168 cap at 3 waves.
template<int NT>
__global__ __launch_bounds__(256, 3) void gemm_xlr(const _Float16* __restrict__ A,
                                                   const _Float16* __restrict__ Bt,
                                                   _Float16* __restrict__ C) {
    constexpr int NY = NT / 128;
    int bx = blockIdx.x / NY;
    int by = blockIdx.x % NY;
    int w = threadIdx.x >> 6, lane = threadIdx.x & 63;
    int m0 = bx * 128 + (w & 1) * 64;
    int n0 = by * 128 + (w >> 1) * 64;
    int q = lane >> 4, li = lane & 15;
    f32x4 acc[4][4] = {};
    const _Float16* Ap[4];
#pragma unroll
    for (int a = 0; a < 4; ++a) {
        int row = m0 + 16 * a + li;
        if (row > N_NODES - 1) row = N_NODES - 1;  // clamp: no OOB reads
        Ap[a] = A + (size_t)row * 128 + q * 8;
    }
    const _Float16* Bp = Bt + (size_t)(n0 + li) * 128 + q * 8;

    v8h afA[4], bfA[4], afB[4], bfB[4];
#pragma unroll
    for (int a = 0; a < 4; ++a) afA[a] = *(const v8h*)(Ap[a]);
#pragma unroll
    for (int b = 0; b < 4; ++b) bfA[b] = *(const v8h*)(Bp + (size_t)(16 * b) * 128);
#pragma unroll
    for (int kt = 0; kt < 4; kt += 2) {
        if (kt + 1 < 4) {
#pragma unroll
            for (int a = 0; a < 4; ++a) afB[a] = *(const v8h*)(Ap[a] + (kt + 1) * 32);
#pragma unroll
            for (int b = 0; b < 4; ++b) bfB[b] = *(const v8h*)(Bp + (size_t)(16 * b) * 128 + (kt + 1) * 32);
        }
#pragma unroll
        for (int a = 0; a < 4; ++a)
#pragma unroll
            for (int b = 0; b < 4; ++b)
                acc[a][b] = __builtin_amdgcn_mfma_f32_16x16x32_f16(bfA[b], afA[a], acc[a][b], 0, 0, 0);
        if (kt + 2 < 4) {
#pragma unroll
            for (int a = 0; a < 4; ++a) afA[a] = *(const v8h*)(Ap[a] + (kt + 2) * 32);
#pragma unroll
            for (int b = 0; b < 4; ++b) bfA[b] = *(const v8h*)(Bp + (size_t)(16 * b) * 128 + (kt + 2) * 32);
        }
#pragma unroll
        for (int a = 0; a < 4; ++a)
#pragma unroll
            for (int b = 0; b < 4; ++b)
                acc[a][b] = __builtin_amdgcn_mfma_f32_16x16x32_f16(bfB[b], afB[a], acc[a][b], 0, 0, 0);
    }
#pragma unroll
    for (int a = 0; a < 4; ++a) {
        int m = m0 + 16 * a + li;
        if (m < N_NODES) {
#pragma unroll
            for (int b = 0; b < 4; ++b) {
                h4 t;
                t[0] = (_Float16)acc[a][b][0]; t[1] = (_Float16)acc[a][b][1];
                t[2] = (_Float16)acc[a][b][2]; t[3] = (_Float16)acc[a][b][3];
                *(h4*)(C + (size_t)m * NT + n0 + 16 * b + 4 * q) = t;
            }
        }
    }
}

// ========== fused GATv2 (R18-proven, REVERTED after R19/R20 persistent-wave failure) =====
// R15: decoupled index/row pipeline (rows depth-3, index 1 iter ahead) -> 52.5->43.3us.
// R16: DPP 8-lane reduce, exp2-domain att, rcp (43.0us proven).
// R18: 3-slot modulo schedule, zero rotation movs (43.2us, flat = at local optimum).
// R19/R20: persistent waves + cross-node pipeline FALSIFIED (R19 spilled; R20 no-spill
// still 55.9us: occupancy 33% from static-assignment tail, serial state rotation).
// One node per wave + HW scheduler rebalancing wins. Do not revisit.
template<int HOUT, typename OUT_T>
__global__ __launch_bounds__(256, 8) void fused_gat(
    const _Float16* __restrict__ XLR,   // [N][2*HOUT] = [xl | xr]
    const int* __restrict__ off, const int* __restrict__ csr,
    const float* __restrict__ att, const float* __restrict__ bias,
    OUT_T* __restrict__ out) {          // [N][HOUT]
    constexpr int VEC = 8;
    constexpr int LPE = HOUT / VEC;     // lanes per edge (16 or 8)
    constexpr int EPW = 64 / LPE;       // edge groups per wave (4 or 8)
    constexpr int ST = 2 * HOUT;
    int wave = threadIdx.x >> 6, lane = threadIdx.x & 63;
    int node = blockIdx.x * (blockDim.x >> 6) + wave;
    if (node >= N_NODES) return;
    int g = lane / LPE;
    int lg = lane % LPE;
    int cb = lg * VEC;

    constexpr float LOG2E = 1.44269504088896340736f;
    f32x2 at2[4], xr2[4];
#pragma unroll
    for (int j = 0; j < 4; ++j) {
        at2[j][0] = att[cb + 2 * j] * LOG2E;       // fold log2e -> exp2 domain
        at2[j][1] = att[cb + 2 * j + 1] * LOG2E;
    }
    v8h xrh = *(const v8h*)(XLR + (size_t)node * ST + HOUT + cb);
    {
        const h2* x2 = (const h2*)&xrh;
#pragma unroll
        for (int j = 0; j < 4; ++j) { xr2[j][0] = (float)x2[j][0]; xr2[j][1] = (float)x2[j][1]; }
    }

    int eoff = off[node];
    int P = off[node + 1] - eoff + 1;   // position 0 = self-loop, 1..deg = csr edges
    float denom = 0.f;
    f32x2 acc2[4] = {};

    const int* cp = csr + eoff;
    const _Float16* Xcb = XLR + cb;
    int pmax_i = P - 2;                  // last valid csr index for this node

    // clamped csr index for position pos (pos >= 1): clamp(pos-1, 0, P-2)
    auto cidx = [&](int pos) -> int {
        int i = pos - 1;
        i = i > pmax_i ? pmax_i : i;
        return i < 0 ? 0 : i;
    };
    // clamped row load (src index garbage-safe)
    auto rowload = [&](int s) -> v8h {
        s = s < 0 ? 0 : s;
        s = s > N_NODES - 1 ? N_NODES - 1 : s;
        return *(const v8h*)(Xcb + (size_t)s * ST);
    };

    int p = g;
    // prologue: indices first (independent loads), then rows as they resolve
    int i1  = cp[cidx(p + EPW)];
    int i2  = cp[cidx(p + 2 * EPW)];
    int si3 = cp[cidx(p + 3 * EPW)];
    int s0  = (p == 0) ? node : cp[cidx(p)];
    v8h ah0 = rowload(s0);
    v8h ah1 = rowload(i1);
    v8h ah2 = rowload(i2);

    // one pipeline step on slot CUR: consume row(p), reload CUR with row(p+3*EPW)
    // (index si3 resolved last step), fetch idx(p+4*EPW), advance p.
    auto do_iter = [&](v8h& cur) {
        const h2* c2 = (const h2*)&cur;
        f32x2 a2[4];
#pragma unroll
        for (int j = 0; j < 4; ++j) { a2[j][0] = (float)c2[j][0]; a2[j][1] = (float)c2[j][1]; }
        cur = rowload(si3);              // slot free after cvt; depth-3 prefetch
        si3 = cp[cidx(p + 4 * EPW)];     // index for next step's row issue (old p!)

        f32x2 sdot = {0.f, 0.f};
#pragma unroll
        for (int j = 0; j < 4; ++j) {
            f32x2 v = a2[j] + xr2[j];
            f32x2 vn = v * NEG_SLOPE;
            f32x2 lv;
            lv[0] = fmaxf(v[0], vn[0]); lv[1] = fmaxf(v[1], vn[1]);
            sdot += at2[j] * lv;
        }
        float s = sdot[0] + sdot[1];
        s = dpp_xadd<0xB1>(s);           // quad_perm [1,0,3,2]
        s = dpp_xadd<0x4E>(s);           // quad_perm [2,3,0,1]
        s = dpp_xadd<0x141>(s);          // row_half_mirror: i <-> 7-i within 8
        float f = exp2f(s);              // att pre-scaled by log2e
        denom += f;
        f32x2 f2 = {f, f};
#pragma unroll
        for (int j = 0; j < 4; ++j) acc2[j] += a2[j] * f2;   // v_pk_fma_f32
        p += EPW;
    };

    while (p < P) {
        do_iter(ah0);
        if (p >= P) break;
        do_iter(ah1);
        if (p >= P) break;
        do_iter(ah2);
    }
#pragma unroll
    for (int o = LPE; o < 64; o <<= 1) {
#pragma unroll
        for (int j = 0; j < 4; ++j) {
            acc2[j][0] += __shfl_xor(acc2[j][0], o);
            acc2[j][1] += __shfl_xor(acc2[j][1], o);
        }
        denom += __shfl_xor(denom, o);
    }
    if (lane < LPE) {
        float inv = __builtin_amdgcn_rcpf(denom);   // approx rcp, once per node
        OUT_T* orow = out + (size_t)node * HOUT + cb;
#pragma unroll
        for (int j = 0; j < 4; ++j) {
#pragma unroll
            for (int t = 0; t < 2; ++t) {
                float r = acc2[j][t] * inv + bias[cb + 2 * j + t];
                r = r > 0.f ? r : (__expf(r) - 1.f);    // elu via fast exp
                orow[2 * j + t] = (OUT_T)r;
            }
        }
    }
}

extern "C" void kernel_launch(void* const* d_in, const int* in_sizes, int n_in,
                              void* d_out, int out_size, void* d_ws, size_t ws_size,
                              hipStream_t stream) {
    const float* x    = (const float*)d_in[0];
    const int*   ei   = (const int*)d_in[1];
    const int*   esrc = ei;
    const int*   edst = ei + N_EDGES;
    const float* W1l = (const float*)d_in[2];
    const float* W1r = (const float*)d_in[3];
    const float* att1= (const float*)d_in[4];
    const float* b1  = (const float*)d_in[5];
    const float* W2l = (const float*)d_in[6];
    const float* W2r = (const float*)d_in[7];
    const float* att2= (const float*)d_in[8];
    const float* b2  = (const float*)d_in[9];
    const float* W3l = (const float*)d_in[10];
    const float* W3r = (const float*)d_in[11];
    const float* att3= (const float*)d_in[12];
    const float* b3  = (const float*)d_in[13];
    float* out = (float*)d_out;

    // ---- workspace layout ----
    _Float16* XLR = (_Float16*)d_ws;                    // 50000*256
    _Float16* Hb  = XLR + (size_t)N_NODES * 256;        // 50000*128
    _Float16* Wt1 = Hb + (size_t)N_NODES * 128;         // 256*128
    _Float16* Wt2 = Wt1 + 256 * 128;                    // 256*128
    _Float16* Wt3 = Wt2 + 256 * 128;                    // 128*128
    int* bcnt = (int*)(Wt3 + 128 * 128);                // 512
    int* off  = bcnt + N_BKT;                           // 50001 (+1 pad)
    int* csr  = off + N_NODES + 1 + 1;                  // 800000
    int2* tmp = (int2*)(csr + N_EDGES);                 // N_BKT*BCAP int2 = 16.8 MB

    const int TB = 256;

    // ---- CSR build + weight prep; layer-1 GEMM merged with CSR finalize ----
    pack_weights_zero<<<cdiv(81920 + N_BKT, TB), TB, 0, stream>>>(
        W1l, W1r, W2l, W2r, W3l, W3r, Wt1, Wt2, Wt3, bcnt);
    bucket_scatter<<<cdiv(N_EDGES, CHUNK), 512, 0, stream>>>(esrc, edst, bcnt, tmp);
    csr_and_gemm1<<<NB_CSR + G1_BLOCKS, 256, 0, stream>>>(bcnt, tmp, off, csr, x, Wt1, XLR);

    const int WPB = 2;                  // R16: finer block retirement vs degree imbalance
    int gat_grid = cdiv(N_NODES, WPB);
    dim3 g2(cdiv(N_NODES, 128) * 2), g1(cdiv(N_NODES, 128));

    // ---- layer 1 ----
    fused_gat<128, _Float16><<<gat_grid, WPB * 64, 0, stream>>>(XLR, off, csr, att1, b1, Hb);
    // ---- layer 2 ----
    gemm_xlr<256><<<g2, 256, 0, stream>>>(Hb, Wt2, XLR);
    fused_gat<128, _Float16><<<gat_grid, WPB * 64, 0, stream>>>(XLR, off, csr, att2, b2, Hb);
    // ---- layer 3 ----
    gemm_xlr<128><<<g1, 256, 0, stream>>>(Hb, Wt3, XLR);
    fused_gat<64, float><<<gat_grid, WPB * 64, 0, stream>>>(XLR, off, csr, att3, b3, out);
}

// Round 8
// 284.920 us; speedup vs baseline: 1.4937x; 1.0190x over previous
//
#include <hip/hip_runtime.h>
#include <hip/hip_fp16.h>
#include <math.h>

#define N_NODES 50000
#define N_EDGES 800000
#define NEG_SLOPE 0.2f

#define BKT_SHIFT 7
#define N_BKT 512                      // pow2 upper bound; used: ceil(50000/128)=391
#define NB_CSR ((N_NODES + 127) / 128) // 391
#define CHUNK 2048                     // edges per phase-A block
#define NB_SCAT ((N_EDGES + CHUNK - 1) / CHUNK)   // 391 scatter blocks
#define PACK_BLOCKS 160                // 81920 pack items / 512 threads
#define BCAP 4096                      // fixed bucket capacity (mean 2048, 45 sigma)
#define PB_CAP 4096
#define G1_BLOCKS (((N_NODES + 127) / 128) * 2)   // 782 gemm-1 blocks (2 n-tiles)

typedef _Float16 v8h __attribute__((ext_vector_type(8)));
typedef _Float16 h4  __attribute__((ext_vector_type(4)));
typedef _Float16 h2  __attribute__((ext_vector_type(2)));
typedef float f32x4 __attribute__((ext_vector_type(4)));
typedef float f32x2 __attribute__((ext_vector_type(2)));

static inline int cdiv(long long a, int b) { return (int)((a + b - 1) / b); }

// DPP-fused butterfly add step (VALU add reading neighbor via DPP, no LDS).
// CTRL: 0xB1 = quad_perm[1,0,3,2] (xor1), 0x4E = quad_perm[2,3,0,1] (xor2),
// 0x141 = row_half_mirror (lane i <-> 7-i within each 8-lane half).
template<int CTRL>
static __device__ __forceinline__ float dpp_xadd(float s) {
    int t = __builtin_amdgcn_mov_dpp(__builtin_bit_cast(int, s), CTRL, 0xf, 0xf, true);
    return s + __builtin_bit_cast(float, t);
}

// ===== Merged dispatch: blocks [0,391) = bucket scatter; [391, 551) = weight packing =====
// R22: pack_weights launch removed — its work rides as tail blocks here (Wt* consumed
// only by the NEXT dispatch, so no intra-dispatch ordering needed). bcnt zero-init moved
// to a hipMemsetAsync before this kernel (removes the zero/atomicAdd race that forced
// the separate launch).
__global__ __launch_bounds__(512) void scatter_and_pack(const int* __restrict__ esrc,
                                                        const int* __restrict__ edst,
                                                        int* __restrict__ bcnt,
                                                        int2* __restrict__ tmp,
                                                        const float* __restrict__ W1l,
                                                        const float* __restrict__ W1r,
                                                        const float* __restrict__ W2l,
                                                        const float* __restrict__ W2r,
                                                        const float* __restrict__ W3l,
                                                        const float* __restrict__ W3r,
                                                        _Float16* __restrict__ Wt1,
                                                        _Float16* __restrict__ Wt2,
                                                        _Float16* __restrict__ Wt3) {
    __shared__ int lhist[N_BKT];
    __shared__ int lscan[N_BKT];
    __shared__ int lofs[N_BKT];
    __shared__ int lcur[N_BKT];
    __shared__ int gbase[N_BKT];
    __shared__ int2 lpair[CHUNK];
    int tid = threadIdx.x;

    if (blockIdx.x >= NB_SCAT) {
        // ---------------- weight packing tail blocks (no LDS, no barriers) ----------------
        int id = (blockIdx.x - NB_SCAT) * 512 + tid;
        if (id < 32768) {                       // Wt1: [256][128]
            int n = id >> 7, k = id & 127;
            Wt1[id] = (_Float16)(n < 128 ? W1l[k * 128 + n] : W1r[k * 128 + n - 128]);
        } else if (id < 65536) {                // Wt2: [256][128]
            int j = id - 32768; int n = j >> 7, k = j & 127;
            Wt2[j] = (_Float16)(n < 128 ? W2l[k * 128 + n] : W2r[k * 128 + n - 128]);
        } else if (id < 81920) {                // Wt3: [128][128]
            int j = id - 65536; int n = j >> 7, k = j & 127;
            Wt3[j] = (_Float16)(n < 64 ? W3l[k * 64 + n] : W3r[k * 64 + n - 64]);
        }
        return;
    }

    int base_e = blockIdx.x * CHUNK;
    int count = min(CHUNK, N_EDGES - base_e);

    if (tid < N_BKT) lhist[tid] = 0;
    __syncthreads();

    int e0 = base_e + tid * 4;
    int4 s4 = {0, 0, 0, 0}, d4 = {0, 0, 0, 0};
    int nmine = 0;
    if (e0 + 3 < N_EDGES && e0 + 3 < base_e + count) {
        s4 = *(const int4*)(esrc + e0);
        d4 = *(const int4*)(edst + e0);
        nmine = 4;
    } else if (e0 < N_EDGES) {
        nmine = min(N_EDGES - e0, 4);
        const int* sp = esrc + e0;
        const int* dp = edst + e0;
        if (nmine > 0) { s4.x = sp[0]; d4.x = dp[0]; }
        if (nmine > 1) { s4.y = sp[1]; d4.y = dp[1]; }
        if (nmine > 2) { s4.z = sp[2]; d4.z = dp[2]; }
    }
    int ds[4] = {d4.x, d4.y, d4.z, d4.w};
    int ss[4] = {s4.x, s4.y, s4.z, s4.w};
#pragma unroll
    for (int u = 0; u < 4; ++u)
        if (u < nmine) atomicAdd(&lhist[ds[u] >> BKT_SHIFT], 1);
    __syncthreads();

    // exclusive scan over N_BKT in LDS (Hillis-Steele, 512 threads = N_BKT)
    int v = lhist[tid];
    lscan[tid] = v;
    __syncthreads();
    for (int st = 1; st < N_BKT; st <<= 1) {
        int t = (tid >= st) ? lscan[tid - st] : 0;
        __syncthreads();
        lscan[tid] += t;
        __syncthreads();
    }
    {
        int excl = lscan[tid] - v;
        lofs[tid] = excl;
        lcur[tid] = excl;
        if (v > 0) gbase[tid] = tid * BCAP + atomicAdd(&bcnt[tid], v);
    }
    __syncthreads();

#pragma unroll
    for (int u = 0; u < 4; ++u)
        if (u < nmine) {
            int b = ds[u] >> BKT_SHIFT;
            int p = atomicAdd(&lcur[b], 1);
            lpair[p] = make_int2(ss[u], ds[u]);
        }
    __syncthreads();

    for (int j = tid; j < count; j += 512) {
        int2 pr = lpair[j];
        int b = pr.y >> BKT_SHIFT;
        int idx = gbase[b] + (j - lofs[b]);
        if (idx < (b + 1) * BCAP) tmp[idx] = pr;   // 45-sigma overflow guard
    }
}

// ===== Merged dispatch: blocks [0,391) finalize CSR; blocks [391, 391+782) run layer-1 GEMM =====
// R15: n-tile (by) fastest-varying so both n-tiles of a bx run temporally adjacent -> the
// f32 A rows (25.6MB) are read once from HBM, second read hits L2/L3.
// R22: gemm inner loop reverted to the simple R16 form (R21 explicit double-buffer was
// not a measurable win; compiler already hoists loads across the unrolled kt rounds).
__global__ __launch_bounds__(256, 2) void csr_and_gemm1(const int* __restrict__ bcnt,
                                                        const int2* __restrict__ tmp,
                                                        int* __restrict__ off,
                                                        int* __restrict__ csr,
                                                        const float* __restrict__ A,
                                                        const _Float16* __restrict__ Bt,
                                                        _Float16* __restrict__ C) {
    __shared__ int red[256];
    __shared__ int lcnt[128];
    __shared__ int sc[128];
    __shared__ int loff[129];
    __shared__ int lcur[128];
    __shared__ int lcsr[PB_CAP];
    int tid = threadIdx.x;

    if (blockIdx.x >= NB_CSR) {
        // ---------------- layer-1 GEMM part (A = f32 input, cast in-register) ------------
        int gb = blockIdx.x - NB_CSR;
        int bx = gb >> 1;               // R15: by fastest for A-row temporal reuse
        int by = gb & 1;                // 0 or 1
        int w = tid >> 6, lane = tid & 63;
        int m0 = bx * 128 + (w & 1) * 64;
        int n0 = by * 128 + (w >> 1) * 64;
        int q = lane >> 4, li = lane & 15;
        f32x4 acc[4][4] = {};
        const float* Ap[4];
#pragma unroll
        for (int a = 0; a < 4; ++a) {
            int row = m0 + 16 * a + li;
            if (row > N_NODES - 1) row = N_NODES - 1;
            Ap[a] = A + (size_t)row * 128 + q * 8;
        }
        const _Float16* Bp = Bt + (size_t)(n0 + li) * 128 + q * 8;
#pragma unroll
        for (int kt = 0; kt < 4; ++kt) {
            v8h af[4], bf[4];
#pragma unroll
            for (int a = 0; a < 4; ++a) {
                float4 lo = *(const float4*)(Ap[a] + kt * 32);
                float4 hi = *(const float4*)(Ap[a] + kt * 32 + 4);
                v8h t;
                t[0] = (_Float16)lo.x; t[1] = (_Float16)lo.y; t[2] = (_Float16)lo.z; t[3] = (_Float16)lo.w;
                t[4] = (_Float16)hi.x; t[5] = (_Float16)hi.y; t[6] = (_Float16)hi.z; t[7] = (_Float16)hi.w;
                af[a] = t;
            }
#pragma unroll
            for (int b = 0; b < 4; ++b) bf[b] = *(const v8h*)(Bp + (size_t)(16 * b) * 128 + kt * 32);
#pragma unroll
            for (int a = 0; a < 4; ++a)
#pragma unroll
                for (int b = 0; b < 4; ++b)
                    acc[a][b] = __builtin_amdgcn_mfma_f32_16x16x32_f16(bf[b], af[a], acc[a][b], 0, 0, 0);
        }
#pragma unroll
        for (int a = 0; a < 4; ++a) {
            int m = m0 + 16 * a + li;
            if (m < N_NODES) {
#pragma unroll
                for (int b = 0; b < 4; ++b) {
                    h4 t;
                    t[0] = (_Float16)acc[a][b][0]; t[1] = (_Float16)acc[a][b][1];
                    t[2] = (_Float16)acc[a][b][2]; t[3] = (_Float16)acc[a][b][3];
                    *(h4*)(C + (size_t)m * 256 + n0 + 16 * b + 4 * q) = t;
                }
            }
        }
        return;
    }

    // ---------------- CSR finalize part ----------------
    int b = blockIdx.x;
    int d0 = b << BKT_SHIFT;
    int dend = min(d0 + 128, N_NODES);
    int nn = dend - d0;

    int pre = 0;
    for (int i = tid; i < b; i += 256) pre += bcnt[i];
    red[tid] = pre;
    __syncthreads();
    for (int st = 128; st > 0; st >>= 1) {
        if (tid < st) red[tid] += red[tid + st];
        __syncthreads();
    }
    int base = red[0];
    __syncthreads();

    int n = min(bcnt[b], BCAP);
    int tbase = b * BCAP;

    if (tid < 128) lcnt[tid] = 0;
    __syncthreads();
    for (int j = tid; j < n; j += 256) {
        int dl = tmp[tbase + j].y - d0;
        atomicAdd(&lcnt[dl], 1);
    }
    __syncthreads();

    if (tid < 128) sc[tid] = lcnt[tid];
    __syncthreads();
    for (int st = 1; st < 128; st <<= 1) {
        int t = (tid < 128 && tid >= st) ? sc[tid - st] : 0;
        __syncthreads();
        if (tid < 128) sc[tid] += t;
        __syncthreads();
    }
    if (tid < 128) loff[tid + 1] = sc[tid];
    if (tid == 0) loff[0] = 0;
    if (tid < 128) lcur[tid] = 0;
    __syncthreads();

    if (tid < nn) off[d0 + tid] = base + loff[tid];
    if (tid == 0 && dend == N_NODES) off[N_NODES] = base + loff[nn];

    for (int j = tid; j < n; j += 256) {
        int2 pr = tmp[tbase + j];
        int dl = pr.y - d0;
        int r = atomicAdd(&lcur[dl], 1);
        int pos = loff[dl] + r;
        if (pos < PB_CAP) lcsr[pos] = pr.x;
    }
    __syncthreads();
    for (int j = tid; j < n; j += 256) csr[base + j] = lcsr[j];
}

// ===== MFMA GEMM (layers 2,3): C[M][NT](f16) = A[M][128] @ Bt[NT][128]^T =====
// R15: 1-D grid, n-tile fastest (A reuse in L2/L3). R22: reverted to simple R16 form,
// __launch_bounds__(256,3) — the proven config (R17's 4-wave cap and R21's explicit
// double-buffer were both neutral-to-negative).
template<int NT>
__global__ __launch_bounds__(256, 3) void gemm_xlr(const _Float16* __restrict__ A,
                                                   const _Float16* __restrict__ Bt,
                                                   _Float16* __restrict__ C) {
    constexpr int NY = NT / 128;
    int bx = blockIdx.x / NY;
    int by = blockIdx.x % NY;
    int w = threadIdx.x >> 6, lane = threadIdx.x & 63;
    int m0 = bx * 128 + (w & 1) * 64;
    int n0 = by * 128 + (w >> 1) * 64;
    int q = lane >> 4, li = lane & 15;
    f32x4 acc[4][4] = {};
    const _Float16* Ap[4];
#pragma unroll
    for (int a = 0; a < 4; ++a) {
        int row = m0 + 16 * a + li;
        if (row > N_NODES - 1) row = N_NODES - 1;  // clamp: no OOB reads
        Ap[a] = A + (size_t)row * 128 + q * 8;
    }
    const _Float16* Bp = Bt + (size_t)(n0 + li) * 128 + q * 8;
#pragma unroll
    for (int kt = 0; kt < 4; ++kt) {
        v8h af[4], bf[4];
#pragma unroll
        for (int a = 0; a < 4; ++a) af[a] = *(const v8h*)(Ap[a] + kt * 32);
#pragma unroll
        for (int b = 0; b < 4; ++b) bf[b] = *(const v8h*)(Bp + (size_t)(16 * b) * 128 + kt * 32);
#pragma unroll
        for (int a = 0; a < 4; ++a)
#pragma unroll
            for (int b = 0; b < 4; ++b)
                acc[a][b] = __builtin_amdgcn_mfma_f32_16x16x32_f16(bf[b], af[a], acc[a][b], 0, 0, 0);
    }
#pragma unroll
    for (int a = 0; a < 4; ++a) {
        int m = m0 + 16 * a + li;
        if (m < N_NODES) {
#pragma unroll
            for (int b = 0; b < 4; ++b) {
                h4 t;
                t[0] = (_Float16)acc[a][b][0]; t[1] = (_Float16)acc[a][b][1];
                t[2] = (_Float16)acc[a][b][2]; t[3] = (_Float16)acc[a][b][3];
                *(h4*)(C + (size_t)m * NT + n0 + 16 * b + 4 * q) = t;
            }
        }
    }
}

// ========== fused GATv2 (R18-proven structure — at its pattern roofline) ==========
// R15: decoupled index/row pipeline (rows depth-3, index 1 iter ahead) -> 52.5->43.3us.
// R16: DPP 8-lane reduce, exp2-domain att, rcp (43.0us proven).
// R18: 3-slot modulo schedule, zero rotation movs (43.2us).
// R19/R20: persistent waves FALSIFIED (spill / 33% occupancy). One node per wave wins.
// Roofline note: 100MB traffic @ ~2.4TB/s effective (random 256B-granule gather served
// by LLC) ~= 42us — the dispatch time. Bytes are compulsory for a random graph.
template<int HOUT, typename OUT_T>
__global__ __launch_bounds__(256, 8) void fused_gat(
    const _Float16* __restrict__ XLR,   // [N][2*HOUT] = [xl | xr]
    const int* __restrict__ off, const int* __restrict__ csr,
    const float* __restrict__ att, const float* __restrict__ bias,
    OUT_T* __restrict__ out) {          // [N][HOUT]
    constexpr int VEC = 8;
    constexpr int LPE = HOUT / VEC;     // lanes per edge (16 or 8)
    constexpr int EPW = 64 / LPE;       // edge groups per wave (4 or 8)
    constexpr int ST = 2 * HOUT;
    int wave = threadIdx.x >> 6, lane = threadIdx.x & 63;
    int node = blockIdx.x * (blockDim.x >> 6) + wave;
    if (node >= N_NODES) return;
    int g = lane / LPE;
    int lg = lane % LPE;
    int cb = lg * VEC;

    constexpr float LOG2E = 1.44269504088896340736f;
    f32x2 at2[4], xr2[4];
#pragma unroll
    for (int j = 0; j < 4; ++j) {
        at2[j][0] = att[cb + 2 * j] * LOG2E;       // fold log2e -> exp2 domain
        at2[j][1] = att[cb + 2 * j + 1] * LOG2E;
    }
    v8h xrh = *(const v8h*)(XLR + (size_t)node * ST + HOUT + cb);
    {
        const h2* x2 = (const h2*)&xrh;
#pragma unroll
        for (int j = 0; j < 4; ++j) { xr2[j][0] = (float)x2[j][0]; xr2[j][1] = (float)x2[j][1]; }
    }

    int eoff = off[node];
    int P = off[node + 1] - eoff + 1;   // position 0 = self-loop, 1..deg = csr edges
    float denom = 0.f;
    f32x2 acc2[4] = {};

    const int* cp = csr + eoff;
    const _Float16* Xcb = XLR + cb;
    int pmax_i = P - 2;                  // last valid csr index for this node

    // clamped csr index for position pos (pos >= 1): clamp(pos-1, 0, P-2)
    auto cidx = [&](int pos) -> int {
        int i = pos - 1;
        i = i > pmax_i ? pmax_i : i;
        return i < 0 ? 0 : i;
    };
    // clamped row load (src index garbage-safe)
    auto rowload = [&](int s) -> v8h {
        s = s < 0 ? 0 : s;
        s = s > N_NODES - 1 ? N_NODES - 1 : s;
        return *(const v8h*)(Xcb + (size_t)s * ST);
    };

    int p = g;
    // prologue: indices first (independent loads), then rows as they resolve
    int i1  = cp[cidx(p + EPW)];
    int i2  = cp[cidx(p + 2 * EPW)];
    int si3 = cp[cidx(p + 3 * EPW)];
    int s0  = (p == 0) ? node : cp[cidx(p)];
    v8h ah0 = rowload(s0);
    v8h ah1 = rowload(i1);
    v8h ah2 = rowload(i2);

    // one pipeline step on slot CUR: consume row(p), reload CUR with row(p+3*EPW)
    // (index si3 resolved last step), fetch idx(p+4*EPW), advance p.
    auto do_iter = [&](v8h& cur) {
        const h2* c2 = (const h2*)&cur;
        f32x2 a2[4];
#pragma unroll
        for (int j = 0; j < 4; ++j) { a2[j][0] = (float)c2[j][0]; a2[j][1] = (float)c2[j][1]; }
        cur = rowload(si3);              // slot free after cvt; depth-3 prefetch
        si3 = cp[cidx(p + 4 * EPW)];     // index for next step's row issue (old p!)

        f32x2 sdot = {0.f, 0.f};
#pragma unroll
        for (int j = 0; j < 4; ++j) {
            f32x2 v = a2[j] + xr2[j];
            f32x2 vn = v * NEG_SLOPE;
            f32x2 lv;
            lv[0] = fmaxf(v[0], vn[0]); lv[1] = fmaxf(v[1], vn[1]);
            sdot += at2[j] * lv;
        }
        float s = sdot[0] + sdot[1];
        s = dpp_xadd<0xB1>(s);           // quad_perm [1,0,3,2]
        s = dpp_xadd<0x4E>(s);           // quad_perm [2,3,0,1]
        s = dpp_xadd<0x141>(s);          // row_half_mirror: i <-> 7-i within 8
        float f = exp2f(s);              // att pre-scaled by log2e
        denom += f;
        f32x2 f2 = {f, f};
#pragma unroll
        for (int j = 0; j < 4; ++j) acc2[j] += a2[j] * f2;   // v_pk_fma_f32
        p += EPW;
    };

    while (p < P) {
        do_iter(ah0);
        if (p >= P) break;
        do_iter(ah1);
        if (p >= P) break;
        do_iter(ah2);
    }
#pragma unroll
    for (int o = LPE; o < 64; o <<= 1) {
#pragma unroll
        for (int j = 0; j < 4; ++j) {
            acc2[j][0] += __shfl_xor(acc2[j][0], o);
            acc2[j][1] += __shfl_xor(acc2[j][1], o);
        }
        denom += __shfl_xor(denom, o);
    }
    if (lane < LPE) {
        float inv = __builtin_amdgcn_rcpf(denom);   // approx rcp, once per node
        OUT_T* orow = out + (size_t)node * HOUT + cb;
#pragma unroll
        for (int j = 0; j < 4; ++j) {
#pragma unroll
            for (int t = 0; t < 2; ++t) {
                float r = acc2[j][t] * inv + bias[cb + 2 * j + t];
                r = r > 0.f ? r : (__expf(r) - 1.f);    // elu via fast exp
                orow[2 * j + t] = (OUT_T)r;
            }
        }
    }
}

extern "C" void kernel_launch(void* const* d_in, const int* in_sizes, int n_in,
                              void* d_out, int out_size, void* d_ws, size_t ws_size,
                              hipStream_t stream) {
    const float* x    = (const float*)d_in[0];
    const int*   ei   = (const int*)d_in[1];
    const int*   esrc = ei;
    const int*   edst = ei + N_EDGES;
    const float* W1l = (const float*)d_in[2];
    const float* W1r = (const float*)d_in[3];
    const float* att1= (const float*)d_in[4];
    const float* b1  = (const float*)d_in[5];
    const float* W2l = (const float*)d_in[6];
    const float* W2r = (const float*)d_in[7];
    const float* att2= (const float*)d_in[8];
    const float* b2  = (const float*)d_in[9];
    const float* W3l = (const float*)d_in[10];
    const float* W3r = (const float*)d_in[11];
    const float* att3= (const float*)d_in[12];
    const float* b3  = (const float*)d_in[13];
    float* out = (float*)d_out;

    // ---- workspace layout ----
    _Float16* XLR = (_Float16*)d_ws;                    // 50000*256
    _Float16* Hb  = XLR + (size_t)N_NODES * 256;        // 50000*128
    _Float16* Wt1 = Hb + (size_t)N_NODES * 128;         // 256*128
    _Float16* Wt2 = Wt1 + 256 * 128;                    // 256*128
    _Float16* Wt3 = Wt2 + 256 * 128;                    // 128*128
    int* bcnt = (int*)(Wt3 + 128 * 128);                // 512
    int* off  = bcnt + N_BKT;                           // 50001 (+1 pad)
    int* csr  = off + N_NODES + 1 + 1;                  // 800000
    int2* tmp = (int2*)(csr + N_EDGES);                 // N_BKT*BCAP int2 = 16.8 MB

    // ---- CSR build + weight prep (merged); layer-1 GEMM merged with CSR finalize ----
    hipMemsetAsync(bcnt, 0, N_BKT * sizeof(int), stream);   // replaces pack's bcnt zeroing
    scatter_and_pack<<<NB_SCAT + PACK_BLOCKS, 512, 0, stream>>>(
        esrc, edst, bcnt, tmp, W1l, W1r, W2l, W2r, W3l, W3r, Wt1, Wt2, Wt3);
    csr_and_gemm1<<<NB_CSR + G1_BLOCKS, 256, 0, stream>>>(bcnt, tmp, off, csr, x, Wt1, XLR);

    const int WPB = 2;                  // R16: finer block retirement vs degree imbalance
    int gat_grid = cdiv(N_NODES, WPB);
    dim3 g2(cdiv(N_NODES, 128) * 2), g1(cdiv(N_NODES, 128));

    // ---- layer 1 ----
    fused_gat<128, _Float16><<<gat_grid, WPB * 64, 0, stream>>>(XLR, off, csr, att1, b1, Hb);
    // ---- layer 2 ----
    gemm_xlr<256><<<g2, 256, 0, stream>>>(Hb, Wt2, XLR);
    fused_gat<128, _Float16><<<gat_grid, WPB * 64, 0, stream>>>(XLR, off, csr, att2, b2, Hb);
    // ---- layer 3 ----
    gemm_xlr<128><<<g1, 256, 0, stream>>>(Hb, Wt3, XLR);
    fused_gat<64, float><<<gat_grid, WPB * 64, 0, stream>>>(XLR, off, csr, att3, b3, out);
}